// Round 2
// baseline (5369.678 us; speedup 1.0000x reference)
//
#include <hip/hip_runtime.h>
#include <hip/hip_bf16.h>
#include <math.h>

#define N_SEQ  4096
#define DMODEL 320
#define NHEADS 8
#define DHEAD  40
#define CTXN   77
#define CTXD   768
#define FFI    1280

// ---------------- GroupNorm ----------------
__global__ __launch_bounds__(256) void gn_stats_k(const float* __restrict__ x, float* __restrict__ stats) {
    __shared__ float red[512];
    int g = blockIdx.x, t = threadIdx.x;
    const float* xp = x + (size_t)g * 40960;  // 10 channels * 4096
    float s = 0.f, ss = 0.f;
    for (int i = t; i < 40960; i += 256) { float v = xp[i]; s += v; ss += v * v; }
    red[t] = s; red[256 + t] = ss;
    __syncthreads();
    for (int st = 128; st > 0; st >>= 1) {
        if (t < st) { red[t] += red[t + st]; red[256 + t] += red[256 + t + st]; }
        __syncthreads();
    }
    if (t == 0) {
        float mean = red[0] / 40960.f;
        float var  = red[256] / 40960.f - mean * mean;
        stats[2 * g] = mean;
        stats[2 * g + 1] = rsqrtf(var + 1e-6f);
    }
}

__global__ __launch_bounds__(256) void gn_apply_k(const float* __restrict__ x, const float* __restrict__ stats,
                                                  const float* __restrict__ gw, const float* __restrict__ gb,
                                                  float* __restrict__ out) {
    int e = blockIdx.x * 256 + threadIdx.x;   // < 1310720
    int c = e >> 12;
    int g = c / 10;
    float v = (x[e] - stats[2 * g]) * stats[2 * g + 1] * gw[c] + gb[c];
    out[e] = v;   // layout [C][HW], same as x
}

// ---------------- LayerNorm (1 wave per row of 320) ----------------
__global__ __launch_bounds__(64) void ln_k(const float* __restrict__ in, const float* __restrict__ w,
                                           const float* __restrict__ b, float* __restrict__ out) {
    int row = blockIdx.x, l = threadIdx.x;
    const float* p = in + (size_t)row * DMODEL;
    float xv[5], s = 0.f, ss = 0.f;
#pragma unroll
    for (int j = 0; j < 5; ++j) { xv[j] = p[l + 64 * j]; s += xv[j]; ss += xv[j] * xv[j]; }
    for (int o = 32; o > 0; o >>= 1) { s += __shfl_xor(s, o); ss += __shfl_xor(ss, o); }
    float mean = s * (1.f / 320.f);
    float var  = ss * (1.f / 320.f) - mean * mean;
    float rstd = rsqrtf(var + 1e-5f);
    float* q = out + (size_t)row * DMODEL;
#pragma unroll
    for (int j = 0; j < 5; ++j) {
        int i = l + 64 * j;
        q[i] = (xv[j] - mean) * rstd * w[i] + b[i];
    }
}

// ---------------- Generic fp32 GEMM: out[n,o] = sum_i A[n*asn+i*asi] * W[i*wsi+o*wso] (+bias)(+res)(GEGLU) ---
// 64x64 tile, 256 threads, 4x4 per thread, K-tile 16.
__global__ __launch_bounds__(256) void matmul_k(const float* __restrict__ A, int asn, int asi,
                                                const float* __restrict__ W, int wsi, int wso,
                                                const float* __restrict__ bias,
                                                const float* __restrict__ res,
                                                float* __restrict__ out,
                                                int Mrows, int K, int Oout, int geglu_off) {
    __shared__ __align__(16) float As[16][64];
    __shared__ __align__(16) float Ws[16][64];
    __shared__ __align__(16) float Wg[16][64];
    const int t = threadIdx.x;
    const int o0 = blockIdx.x * 64;
    const int n0 = blockIdx.y * 64;
    const int tx = t & 15, ty = t >> 4;
    const bool geglu = (geglu_off > 0);

    float acc[4][4] = {{0.f}};
    float accg[4][4] = {{0.f}};

    for (int k0 = 0; k0 < K; k0 += 16) {
        __syncthreads();
        if (asi == 1) {  // A row-major [n][K]
#pragma unroll
            for (int j = 0; j < 4; ++j) {
                int e = t + 256 * j; int kk = e & 15, nn = e >> 4;
                int n = n0 + nn;
                As[kk][nn] = (n < Mrows) ? A[(size_t)n * asn + (k0 + kk)] : 0.f;
            }
        } else {         // A is [K][n] (asn==1)
#pragma unroll
            for (int j = 0; j < 4; ++j) {
                int e = t + 256 * j; int nn = e & 63, kk = e >> 6;
                int n = n0 + nn;
                As[kk][nn] = (n < Mrows) ? A[(size_t)(k0 + kk) * asi + n] : 0.f;
            }
        }
#pragma unroll
        for (int j = 0; j < 4; ++j) {
            int e = t + 256 * j; int oo = e & 63, kk = e >> 6;
            int o = o0 + oo;
            Ws[kk][oo] = (o < Oout) ? W[(size_t)(k0 + kk) * wsi + (size_t)o * wso] : 0.f;
        }
        if (geglu) {
#pragma unroll
            for (int j = 0; j < 4; ++j) {
                int e = t + 256 * j; int oo = e & 63, kk = e >> 6;
                int o = o0 + oo;
                Wg[kk][oo] = (o < Oout) ? W[(size_t)(k0 + kk) * wsi + (size_t)(o + geglu_off) * wso] : 0.f;
            }
        }
        __syncthreads();
#pragma unroll
        for (int kk = 0; kk < 16; ++kk) {
            float4 avv = *(const float4*)&As[kk][ty * 4];
            float4 wvv = *(const float4*)&Ws[kk][tx * 4];
            float a4[4] = {avv.x, avv.y, avv.z, avv.w};
            float w4[4] = {wvv.x, wvv.y, wvv.z, wvv.w};
#pragma unroll
            for (int i = 0; i < 4; ++i)
#pragma unroll
                for (int j = 0; j < 4; ++j) acc[i][j] += a4[i] * w4[j];
            if (geglu) {
                float4 gvv = *(const float4*)&Wg[kk][tx * 4];
                float g4[4] = {gvv.x, gvv.y, gvv.z, gvv.w};
#pragma unroll
                for (int i = 0; i < 4; ++i)
#pragma unroll
                    for (int j = 0; j < 4; ++j) accg[i][j] += a4[i] * g4[j];
            }
        }
    }
#pragma unroll
    for (int i = 0; i < 4; ++i) {
        int n = n0 + ty * 4 + i;
        if (n >= Mrows) continue;
#pragma unroll
        for (int j = 0; j < 4; ++j) {
            int o = o0 + tx * 4 + j;
            if (o >= Oout) continue;
            float v = acc[i][j] + (bias ? bias[o] : 0.f);
            if (geglu) {
                float g = accg[i][j] + bias[o + geglu_off];
                v = v * 0.5f * g * (1.f + erff(g * 0.70710678118654752f));
            }
            if (res) v += res[(size_t)n * Oout + o];
            out[(size_t)n * Oout + o] = v;
        }
    }
}

// ---------------- Self-attention (flash, online softmax) ----------------
// grid (64 qtiles, 8 heads), block 256. Thread: row r=t>>2 (local), qq=t&3 -> dims qq*10..+10.
// K/V read from global (L2-resident); only P round-trips LDS (intra-wave, no barriers).
__global__ __launch_bounds__(256) void attn_self_k(const float* __restrict__ q, const float* __restrict__ k,
                                                   const float* __restrict__ v, float* __restrict__ out) {
    __shared__ __align__(16) float Ps[64][64];
    const int t = threadIdx.x;
    const int hd = blockIdx.y;
    const int q0 = blockIdx.x * 64;
    const int r = t >> 2, qq = t & 3;
    const float scale = 0.15811388300841897f;  // 1/sqrt(40)
    float4 qr[10];
    {
        const float* qp = q + (size_t)(q0 + r) * DMODEL + hd * DHEAD;
#pragma unroll
        for (int i = 0; i < 10; ++i) {
            float4 t4 = ((const float4*)qp)[i];
            qr[i] = make_float4(t4.x * scale, t4.y * scale, t4.z * scale, t4.w * scale);
        }
    }
    float m = -1e30f, l = 0.f;
    float O[10] = {0.f};
    const int d0 = qq * 10;

    for (int kt = 0; kt < 64; ++kt) {
        const int k0 = kt * 64;
        float sv[16];
        float mloc = -1e30f;
#pragma unroll 4
        for (int jj = 0; jj < 16; ++jj) {
            const float* kp = k + (size_t)(k0 + qq * 16 + jj) * DMODEL + hd * DHEAD;
            float s = 0.f;
#pragma unroll
            for (int i = 0; i < 10; ++i) {
                float4 kv = ((const float4*)kp)[i];
                s += qr[i].x * kv.x + qr[i].y * kv.y + qr[i].z * kv.z + qr[i].w * kv.w;
            }
            sv[jj] = s;
            mloc = fmaxf(mloc, s);
        }
        mloc = fmaxf(mloc, __shfl_xor(mloc, 1));
        mloc = fmaxf(mloc, __shfl_xor(mloc, 2));
        float mnew = fmaxf(m, mloc);
        float alpha = __expf(m - mnew);
        float psum = 0.f;
#pragma unroll
        for (int jj = 0; jj < 16; ++jj) {
            float p = __expf(sv[jj] - mnew);
            Ps[r][qq * 16 + jj] = p;
            psum += p;
        }
        psum += __shfl_xor(psum, 1);
        psum += __shfl_xor(psum, 2);
        l = l * alpha + psum;
        m = mnew;
#pragma unroll
        for (int dd = 0; dd < 10; ++dd) O[dd] *= alpha;
        // PV: Ps row written by the 4 same-wave lanes of this row -> no barrier needed
#pragma unroll 2
        for (int j4 = 0; j4 < 16; ++j4) {
            float4 p4 = *(const float4*)&Ps[r][j4 * 4];
            float pj[4] = {p4.x, p4.y, p4.z, p4.w};
#pragma unroll
            for (int u = 0; u < 4; ++u) {
                const float* vp = v + (size_t)(k0 + j4 * 4 + u) * DMODEL + hd * DHEAD + d0;
#pragma unroll
                for (int i = 0; i < 5; ++i) {
                    float2 v2 = ((const float2*)vp)[i];
                    O[2 * i]     += pj[u] * v2.x;
                    O[2 * i + 1] += pj[u] * v2.y;
                }
            }
        }
    }
    float inv = 1.f / l;
    float* op = out + (size_t)(q0 + r) * DMODEL + hd * DHEAD + d0;
#pragma unroll
    for (int dd = 0; dd < 10; ++dd) op[dd] = O[dd] * inv;
}

// ---------------- Cross-attention (M=77): one wave per (row, head) ----------------
__global__ __launch_bounds__(256) void attn_cross_k(const float* __restrict__ q, const float* __restrict__ kc,
                                                    const float* __restrict__ vc, float* __restrict__ out) {
    __shared__ float Pl[4][128];
    const int t = threadIdx.x, w = t >> 6, l = t & 63;
    const int gw = blockIdx.x * 4 + w;         // 0..32767
    const int row = gw >> 3, hd = gw & 7;
    const float scale = 0.15811388300841897f;
    float4 qv[10];
    {
        const float* qp = q + (size_t)row * DMODEL + hd * DHEAD;
#pragma unroll
        for (int i = 0; i < 10; ++i) {
            float4 t4 = ((const float4*)qp)[i];
            qv[i] = make_float4(t4.x * scale, t4.y * scale, t4.z * scale, t4.w * scale);
        }
    }
    float s1 = -1e30f, s2 = -1e30f;
    {
        if (l < CTXN) {
            const float* kp = kc + (size_t)l * DMODEL + hd * DHEAD;
            float s = 0.f;
#pragma unroll
            for (int i = 0; i < 10; ++i) {
                float4 kv = ((const float4*)kp)[i];
                s += qv[i].x * kv.x + qv[i].y * kv.y + qv[i].z * kv.z + qv[i].w * kv.w;
            }
            s1 = s;
        }
        if (l + 64 < CTXN) {
            const float* kp2 = kc + (size_t)(l + 64) * DMODEL + hd * DHEAD;
            float s = 0.f;
#pragma unroll
            for (int i = 0; i < 10; ++i) {
                float4 kv = ((const float4*)kp2)[i];
                s += qv[i].x * kv.x + qv[i].y * kv.y + qv[i].z * kv.z + qv[i].w * kv.w;
            }
            s2 = s;
        }
    }
    float mx = fmaxf(s1, s2);
    for (int o = 32; o > 0; o >>= 1) mx = fmaxf(mx, __shfl_xor(mx, o));
    float p1 = (l < CTXN) ? __expf(s1 - mx) : 0.f;
    float p2 = (l + 64 < CTXN) ? __expf(s2 - mx) : 0.f;
    float ps = p1 + p2;
    for (int o = 32; o > 0; o >>= 1) ps += __shfl_xor(ps, o);
    Pl[w][l] = p1;
    Pl[w][l + 64] = p2;
    if (l < DHEAD) {
        float acc = 0.f;
        for (int j = 0; j < CTXN; ++j) acc += Pl[w][j] * vc[(size_t)j * DMODEL + hd * DHEAD + l];
        out[(size_t)row * DMODEL + hd * DHEAD + l] = acc / ps;
    }
}

// ---------------- final: out[c][p] = t0[p][c] + x[c][p] ----------------
__global__ __launch_bounds__(256) void final_k(const float* __restrict__ t0, const float* __restrict__ x,
                                               float* __restrict__ out) {
    int e = blockIdx.x * 256 + threadIdx.x;   // < 1310720
    int c = e >> 12, p = e & 4095;
    out[e] = t0[(size_t)p * DMODEL + c] + x[e];
}

extern "C" void kernel_launch(void* const* d_in, const int* in_sizes, int n_in,
                              void* d_out, int out_size, void* d_ws, size_t ws_size,
                              hipStream_t stream) {
    const float* x      = (const float*)d_in[0];
    const float* ctx    = (const float*)d_in[1];
    const float* gn_w   = (const float*)d_in[2];
    const float* gn_b   = (const float*)d_in[3];
    const float* pin_w  = (const float*)d_in[4];
    const float* pin_b  = (const float*)d_in[5];
    const float* ln1_w  = (const float*)d_in[6];
    const float* ln1_b  = (const float*)d_in[7];
    const float* q1     = (const float*)d_in[8];
    const float* k1     = (const float*)d_in[9];
    const float* v1     = (const float*)d_in[10];
    const float* o1_w   = (const float*)d_in[11];
    const float* o1_b   = (const float*)d_in[12];
    const float* ln2_w  = (const float*)d_in[13];
    const float* ln2_b  = (const float*)d_in[14];
    const float* q2     = (const float*)d_in[15];
    const float* k2     = (const float*)d_in[16];
    const float* v2     = (const float*)d_in[17];
    const float* o2_w   = (const float*)d_in[18];
    const float* o2_b   = (const float*)d_in[19];
    const float* ln3_w  = (const float*)d_in[20];
    const float* ln3_b  = (const float*)d_in[21];
    const float* ff1_w  = (const float*)d_in[22];
    const float* ff1_b  = (const float*)d_in[23];
    const float* ff2_w  = (const float*)d_in[24];
    const float* ff2_b  = (const float*)d_in[25];
    const float* pout_w = (const float*)d_in[26];
    const float* pout_b = (const float*)d_in[27];
    float* out = (float*)d_out;

    // Compact workspace: 64 + 6*NB floats = 31.5 MB
    float* ws    = (float*)d_ws;
    const size_t NB = (size_t)N_SEQ * DMODEL;   // 1310720
    float* stats = ws;                // 64
    float* h     = ws + 64;           // residual stream [4096,320]
    float* t0    = h + NB;            // LN out / attn out (aliased) / pre-final
    float* p0    = t0 + NB;           // q  / gno / ffg[0]
    float* p1    = p0 + NB;           // k  / ffg[1]
    float* p2    = p1 + NB;           // v  / ffg[2]
    float* p3    = p2 + NB;           // k2b,v2b / ffg[3]
    float* gno   = p0;
    float* qb    = p0;
    float* kb    = p1;
    float* vb    = p2;
    float* ao    = t0;                // attention output aliases t0 (t0 dead after q/k/v proj)
    float* ffg   = p0;                // [4096,1280] spans p0..p3 (4*NB exactly)
    float* k2b   = p3;                // [77,320] (pad to 80 rows)
    float* v2b   = p3 + 25600;

    // 1. GroupNorm
    gn_stats_k<<<32, 256, 0, stream>>>(x, stats);
    gn_apply_k<<<5120, 256, 0, stream>>>(x, stats, gn_w, gn_b, gno);
    // 2. proj_in (conv1x1): h[n,o] = sum_i gno[i][n] * pin_w[o,i] + pin_b
    matmul_k<<<dim3(5, 64), 256, 0, stream>>>(gno, 1, 4096, pin_w, 1, 320, pin_b, nullptr, h, 4096, 320, 320, 0);
    // 3. self-attention block
    ln_k<<<4096, 64, 0, stream>>>(h, ln1_w, ln1_b, t0);
    matmul_k<<<dim3(5, 64), 256, 0, stream>>>(t0, 320, 1, q1, 320, 1, nullptr, nullptr, qb, 4096, 320, 320, 0);
    matmul_k<<<dim3(5, 64), 256, 0, stream>>>(t0, 320, 1, k1, 320, 1, nullptr, nullptr, kb, 4096, 320, 320, 0);
    matmul_k<<<dim3(5, 64), 256, 0, stream>>>(t0, 320, 1, v1, 320, 1, nullptr, nullptr, vb, 4096, 320, 320, 0);
    attn_self_k<<<dim3(64, 8), 256, 0, stream>>>(qb, kb, vb, ao);
    matmul_k<<<dim3(5, 64), 256, 0, stream>>>(ao, 320, 1, o1_w, 320, 1, o1_b, h, h, 4096, 320, 320, 0);
    // 4. cross-attention block
    ln_k<<<4096, 64, 0, stream>>>(h, ln2_w, ln2_b, t0);
    matmul_k<<<dim3(5, 64), 256, 0, stream>>>(t0, 320, 1, q2, 320, 1, nullptr, nullptr, qb, 4096, 320, 320, 0);
    matmul_k<<<dim3(5, 2), 256, 0, stream>>>(ctx, 768, 1, k2, 320, 1, nullptr, nullptr, k2b, 77, 768, 320, 0);
    matmul_k<<<dim3(5, 2), 256, 0, stream>>>(ctx, 768, 1, v2, 320, 1, nullptr, nullptr, v2b, 77, 768, 320, 0);
    attn_cross_k<<<8192, 256, 0, stream>>>(qb, k2b, v2b, ao);
    matmul_k<<<dim3(5, 64), 256, 0, stream>>>(ao, 320, 1, o2_w, 320, 1, o2_b, h, h, 4096, 320, 320, 0);
    // 5. GEGLU FF
    ln_k<<<4096, 64, 0, stream>>>(h, ln3_w, ln3_b, t0);
    matmul_k<<<dim3(20, 64), 256, 0, stream>>>(t0, 320, 1, ff1_w, 2560, 1, ff1_b, nullptr, ffg, 4096, 320, 1280, 1280);
    matmul_k<<<dim3(5, 64), 256, 0, stream>>>(ffg, 1280, 1, ff2_w, 320, 1, ff2_b, h, h, 4096, 1280, 320, 0);
    // 6. proj_out + input residual
    matmul_k<<<dim3(5, 64), 256, 0, stream>>>(h, 320, 1, pout_w, 1, 320, pout_b, nullptr, t0, 4096, 320, 320, 0);
    final_k<<<5120, 256, 0, stream>>>(t0, x, out);
}

// Round 4
// 829.132 us; speedup vs baseline: 6.4763x; 6.4763x over previous
//
#include <hip/hip_runtime.h>
#include <hip/hip_bf16.h>
#include <math.h>

#define N_SEQ  4096
#define DMODEL 320
#define NHEADS 8
#define DHEAD  40
#define CTXN   77
#define CTXD   768
#define FFI    1280

typedef short s8v __attribute__((ext_vector_type(8)));
typedef float f4v __attribute__((ext_vector_type(4)));

static __device__ __forceinline__ unsigned short f2bs(float x) {
    union { __hip_bfloat16 h; unsigned short u; } cv; cv.h = __float2bfloat16(x); return cv.u;
}
static __device__ __forceinline__ unsigned int pack2(float a, float b) {
    return (unsigned int)f2bs(a) | ((unsigned int)f2bs(b) << 16);
}

// ---------------- GroupNorm ----------------
__global__ __launch_bounds__(256) void gn_stats_k(const float* __restrict__ x, float* __restrict__ stats) {
    __shared__ float red[512];
    int g = blockIdx.x, t = threadIdx.x;
    const float* xp = x + (size_t)g * 40960;
    float s = 0.f, ss = 0.f;
    for (int i = t; i < 40960; i += 256) { float v = xp[i]; s += v; ss += v * v; }
    red[t] = s; red[256 + t] = ss;
    __syncthreads();
    for (int st = 128; st > 0; st >>= 1) {
        if (t < st) { red[t] += red[t + st]; red[256 + t] += red[256 + t + st]; }
        __syncthreads();
    }
    if (t == 0) {
        float mean = red[0] / 40960.f;
        float var  = red[256] / 40960.f - mean * mean;
        stats[2 * g] = mean;
        stats[2 * g + 1] = rsqrtf(var + 1e-6f);
    }
}

__global__ __launch_bounds__(256) void gn_apply_k(const float* __restrict__ x, const float* __restrict__ stats,
                                                  const float* __restrict__ gw, const float* __restrict__ gb,
                                                  float* __restrict__ out) {
    int e = blockIdx.x * 256 + threadIdx.x;
    int c = e >> 12;
    int g = c / 10;
    out[e] = (x[e] - stats[2 * g]) * stats[2 * g + 1] * gw[c] + gb[c];
}

// ---------------- LayerNorm (1 wave per row of 320) ----------------
__global__ __launch_bounds__(64) void ln_k(const float* __restrict__ in, const float* __restrict__ w,
                                           const float* __restrict__ b, float* __restrict__ out) {
    int row = blockIdx.x, l = threadIdx.x;
    const float* p = in + (size_t)row * DMODEL;
    float xv[5], s = 0.f, ss = 0.f;
#pragma unroll
    for (int j = 0; j < 5; ++j) { xv[j] = p[l + 64 * j]; s += xv[j]; ss += xv[j] * xv[j]; }
    for (int o = 32; o > 0; o >>= 1) { s += __shfl_xor(s, o); ss += __shfl_xor(ss, o); }
    float mean = s * (1.f / 320.f);
    float var  = ss * (1.f / 320.f) - mean * mean;
    float rstd = rsqrtf(var + 1e-5f);
    float* q = out + (size_t)row * DMODEL;
#pragma unroll
    for (int j = 0; j < 5; ++j) {
        int i = l + 64 * j;
        q[i] = (xv[j] - mean) * rstd * w[i] + b[i];
    }
}

// ---------------- bf16 MFMA GEMM ----------------
// out[n,o] = sum_k A[n*asn + k*asi] * W[k*wsi + o*wso]  (+bias)(+GEGLU)(+res), fp32 acc.
// grid (Oout/64, ceil(M/64)); 256 thr = 4 waves; wave w owns rows w*16..+15 x all 64 cols.
// K must be a multiple of 64 (true for all call sites: 320/768/1280).
#define GP 72   // LDS pitch (shorts)
__global__ __launch_bounds__(256) void gemm_bf16_k(const float* __restrict__ A, int asn, int asi,
                                                   const float* __restrict__ W, int wsi, int wso,
                                                   const float* __restrict__ bias,
                                                   const float* __restrict__ res,
                                                   float* __restrict__ out,
                                                   int Mrows, int K, int Oout, int geglu_off) {
    __shared__ __align__(16) unsigned short As[64 * GP];
    __shared__ __align__(16) unsigned short Wsm[64 * GP];
    __shared__ __align__(16) unsigned short Wgm[64 * GP];
    const int t = threadIdx.x;
    const int w = t >> 6, lane = t & 63, c = lane & 15, quad = lane >> 4;
    const int o0 = blockIdx.x * 64, n0 = blockIdx.y * 64;
    const bool geglu = (geglu_off > 0);
    const f4v zero = {0.f, 0.f, 0.f, 0.f};
    f4v acc[4]  = {zero, zero, zero, zero};
    f4v accg[4] = {zero, zero, zero, zero};

    for (int k0 = 0; k0 < K; k0 += 64) {
        __syncthreads();
        // ---- stage A tile [64 rows][64 k] as bf16 ----
        if (asi == 1) {          // row-major A
            int r = t >> 2, seg = t & 3;
            int n = n0 + r;
            unsigned int* dst = (unsigned int*)&As[r * GP + seg * 16];
            if (n < Mrows) {
                const float* src = A + (size_t)n * asn + k0 + seg * 16;
#pragma unroll
                for (int i = 0; i < 8; ++i) dst[i] = pack2(src[2 * i], src[2 * i + 1]);
            } else {
#pragma unroll
                for (int i = 0; i < 8; ++i) dst[i] = 0u;
            }
        } else {                 // column-major A (asn==1): A[k*asi + n]
#pragma unroll
            for (int j = 0; j < 16; ++j) {
                int e = t + 256 * j; int nn = e & 63, kk = e >> 6;
                int n = n0 + nn;
                As[nn * GP + kk] = (n < Mrows) ? f2bs(A[(size_t)(k0 + kk) * asi + n]) : (unsigned short)0;
            }
        }
        // ---- stage W tile transposed: Wsm[oo][kk] = W[k0+kk][o0+oo] ----
        if (wsi == 1) {          // W[o][k] (o-major): coalesce over k
#pragma unroll
            for (int j = 0; j < 16; ++j) {
                int e = t + 256 * j; int kk = e & 63, oo = e >> 6;
                Wsm[oo * GP + kk] = f2bs(W[(size_t)(k0 + kk) + (size_t)(o0 + oo) * wso]);
            }
        } else {                 // W[k][o] (wso==1): coalesce over o
#pragma unroll
            for (int j = 0; j < 16; ++j) {
                int e = t + 256 * j; int oo = e & 63, kk = e >> 6;
                Wsm[oo * GP + kk] = f2bs(W[(size_t)(k0 + kk) * wsi + (o0 + oo)]);
            }
            if (geglu) {
#pragma unroll
                for (int j = 0; j < 16; ++j) {
                    int e = t + 256 * j; int oo = e & 63, kk = e >> 6;
                    Wgm[oo * GP + kk] = f2bs(W[(size_t)(k0 + kk) * wsi + (o0 + oo + geglu_off)]);
                }
            }
        }
        __syncthreads();
        // ---- compute: 8 MFMAs per wave (16 if geglu) ----
        s8v a0 = *(const s8v*)&As[(w * 16 + c) * GP + quad * 8];
        s8v a1 = *(const s8v*)&As[(w * 16 + c) * GP + 32 + quad * 8];
#pragma unroll
        for (int nt = 0; nt < 4; ++nt) {
            s8v b0 = *(const s8v*)&Wsm[(nt * 16 + c) * GP + quad * 8];
            s8v b1 = *(const s8v*)&Wsm[(nt * 16 + c) * GP + 32 + quad * 8];
            acc[nt] = __builtin_amdgcn_mfma_f32_16x16x32_bf16(a0, b0, acc[nt], 0, 0, 0);
            acc[nt] = __builtin_amdgcn_mfma_f32_16x16x32_bf16(a1, b1, acc[nt], 0, 0, 0);
            if (geglu) {
                s8v g0 = *(const s8v*)&Wgm[(nt * 16 + c) * GP + quad * 8];
                s8v g1 = *(const s8v*)&Wgm[(nt * 16 + c) * GP + 32 + quad * 8];
                accg[nt] = __builtin_amdgcn_mfma_f32_16x16x32_bf16(a0, g0, accg[nt], 0, 0, 0);
                accg[nt] = __builtin_amdgcn_mfma_f32_16x16x32_bf16(a1, g1, accg[nt], 0, 0, 0);
            }
        }
    }
    // ---- epilogue: C-layout row = quad*4+r, col = c (within nt 16-block) ----
#pragma unroll
    for (int nt = 0; nt < 4; ++nt) {
#pragma unroll
        for (int r = 0; r < 4; ++r) {
            int n = n0 + w * 16 + quad * 4 + r;
            if (n >= Mrows) continue;
            int o = o0 + nt * 16 + c;
            float v = acc[nt][r] + (bias ? bias[o] : 0.f);
            if (geglu) {
                float g = accg[nt][r] + bias[o + geglu_off];
                v = v * 0.5f * g * (1.f + erff(g * 0.70710678118654752f));
            }
            if (res) v += res[(size_t)n * Oout + o];
            out[(size_t)n * Oout + o] = v;
        }
    }
}

// ---------------- Self-attention: bf16 MFMA flash ----------------
#define APITCH 72
__global__ __launch_bounds__(256) void attn_self_mfma_k(const float* __restrict__ q, const float* __restrict__ k,
                                                        const float* __restrict__ v, float* __restrict__ out) {
    __shared__ __align__(16) unsigned short Qs[64 * APITCH];
    __shared__ __align__(16) unsigned short Ks[64 * APITCH];
    __shared__ __align__(16) unsigned short Vs[48 * APITCH];   // transposed: [dim][key]
    __shared__ __align__(16) unsigned short Ps[64 * APITCH];
    const int t = threadIdx.x;
    const int w = t >> 6, lane = t & 63;
    const int c = lane & 15, quad = lane >> 4;
    const int hd = blockIdx.y;
    const int q0 = blockIdx.x * 64;
    const float scale = 0.15811388300841897f;
    const f4v zero = {0.f, 0.f, 0.f, 0.f};

    for (int i = t; i < 64 * APITCH / 2; i += 256) { ((unsigned int*)Qs)[i] = 0u; ((unsigned int*)Ks)[i] = 0u; }
    for (int i = t; i < 48 * APITCH / 2; i += 256) ((unsigned int*)Vs)[i] = 0u;
    __syncthreads();

    {
        const int r = t >> 2, qd = t & 3;
        const float* qp = q + (size_t)(q0 + r) * DMODEL + hd * DHEAD + qd * 10;
        unsigned int* dst = (unsigned int*)&Qs[r * APITCH + qd * 10];
#pragma unroll
        for (int i = 0; i < 5; ++i) dst[i] = pack2(qp[2 * i] * scale, qp[2 * i + 1] * scale);
    }
    __syncthreads();

    const int mrow = w * 16 + c;
    s8v qa0 = *(const s8v*)&Qs[mrow * APITCH + quad * 8];
    s8v qa1 = *(const s8v*)&Qs[mrow * APITCH + 32 + quad * 8];

    float mr[4] = {-1e30f, -1e30f, -1e30f, -1e30f};
    float lr[4] = {0.f, 0.f, 0.f, 0.f};
    f4v o0 = zero, o1 = zero, o2 = zero;

    for (int kt = 0; kt < 64; ++kt) {
        const int k0 = kt * 64;
        __syncthreads();
        {
            const int r = t >> 2, qd = t & 3;
            const float* kp = k + (size_t)(k0 + r) * DMODEL + hd * DHEAD + qd * 10;
            unsigned int* kd = (unsigned int*)&Ks[r * APITCH + qd * 10];
#pragma unroll
            for (int i = 0; i < 5; ++i) kd[i] = pack2(kp[2 * i], kp[2 * i + 1]);
            const float* vp = v + (size_t)(k0 + r) * DMODEL + hd * DHEAD + qd * 10;
#pragma unroll
            for (int i = 0; i < 10; ++i) Vs[(qd * 10 + i) * APITCH + r] = f2bs(vp[i]);
        }
        __syncthreads();

        f4v sarr[4];
#pragma unroll
        for (int nt = 0; nt < 4; ++nt) {
            s8v kb0 = *(const s8v*)&Ks[(nt * 16 + c) * APITCH + quad * 8];
            s8v kb1 = *(const s8v*)&Ks[(nt * 16 + c) * APITCH + 32 + quad * 8];
            f4v acc = __builtin_amdgcn_mfma_f32_16x16x32_bf16(qa0, kb0, zero, 0, 0, 0);
            acc = __builtin_amdgcn_mfma_f32_16x16x32_bf16(qa1, kb1, acc, 0, 0, 0);
            sarr[nt] = acc;
        }

        float alpha4[4];
#pragma unroll
        for (int r = 0; r < 4; ++r) {
            float mloc = fmaxf(fmaxf(sarr[0][r], sarr[1][r]), fmaxf(sarr[2][r], sarr[3][r]));
            mloc = fmaxf(mloc, __shfl_xor(mloc, 1));
            mloc = fmaxf(mloc, __shfl_xor(mloc, 2));
            mloc = fmaxf(mloc, __shfl_xor(mloc, 4));
            mloc = fmaxf(mloc, __shfl_xor(mloc, 8));
            float mnew = fmaxf(mr[r], mloc);
            alpha4[r] = __expf(mr[r] - mnew);
            mr[r] = mnew;
            float ps = 0.f;
#pragma unroll
            for (int nt = 0; nt < 4; ++nt) {
                float pv = __expf(sarr[nt][r] - mnew);
                ps += pv;
                Ps[(w * 16 + quad * 4 + r) * APITCH + nt * 16 + c] = f2bs(pv);
            }
            ps += __shfl_xor(ps, 1);
            ps += __shfl_xor(ps, 2);
            ps += __shfl_xor(ps, 4);
            ps += __shfl_xor(ps, 8);
            lr[r] = lr[r] * alpha4[r] + ps;
        }
        f4v av = {alpha4[0], alpha4[1], alpha4[2], alpha4[3]};
        o0 *= av; o1 *= av; o2 *= av;

        s8v pa0 = *(const s8v*)&Ps[(w * 16 + c) * APITCH + quad * 8];
        s8v pa1 = *(const s8v*)&Ps[(w * 16 + c) * APITCH + 32 + quad * 8];
        {
            s8v vb0 = *(const s8v*)&Vs[(0 * 16 + c) * APITCH + quad * 8];
            s8v vb1 = *(const s8v*)&Vs[(0 * 16 + c) * APITCH + 32 + quad * 8];
            o0 = __builtin_amdgcn_mfma_f32_16x16x32_bf16(pa0, vb0, o0, 0, 0, 0);
            o0 = __builtin_amdgcn_mfma_f32_16x16x32_bf16(pa1, vb1, o0, 0, 0, 0);
        }
        {
            s8v vb0 = *(const s8v*)&Vs[(1 * 16 + c) * APITCH + quad * 8];
            s8v vb1 = *(const s8v*)&Vs[(1 * 16 + c) * APITCH + 32 + quad * 8];
            o1 = __builtin_amdgcn_mfma_f32_16x16x32_bf16(pa0, vb0, o1, 0, 0, 0);
            o1 = __builtin_amdgcn_mfma_f32_16x16x32_bf16(pa1, vb1, o1, 0, 0, 0);
        }
        {
            s8v vb0 = *(const s8v*)&Vs[(2 * 16 + c) * APITCH + quad * 8];
            s8v vb1 = *(const s8v*)&Vs[(2 * 16 + c) * APITCH + 32 + quad * 8];
            o2 = __builtin_amdgcn_mfma_f32_16x16x32_bf16(pa0, vb0, o2, 0, 0, 0);
            o2 = __builtin_amdgcn_mfma_f32_16x16x32_bf16(pa1, vb1, o2, 0, 0, 0);
        }
    }

    float inv[4];
#pragma unroll
    for (int r = 0; r < 4; ++r) inv[r] = 1.f / lr[r];
#pragma unroll
    for (int r = 0; r < 4; ++r) {
        const size_t row = (size_t)(q0 + w * 16 + quad * 4 + r) * DMODEL + hd * DHEAD;
        out[row + c]      = o0[r] * inv[r];
        out[row + 16 + c] = o1[r] * inv[r];
        if (c < 8) out[row + 32 + c] = o2[r] * inv[r];
    }
}

// ---------------- Cross-attention (M=77): one wave per (row, head) ----------------
__global__ __launch_bounds__(256) void attn_cross_k(const float* __restrict__ q, const float* __restrict__ kc,
                                                    const float* __restrict__ vc, float* __restrict__ out) {
    __shared__ float Pl[4][128];
    const int t = threadIdx.x, w = t >> 6, l = t & 63;
    const int gw = blockIdx.x * 4 + w;
    const int row = gw >> 3, hd = gw & 7;
    const float scale = 0.15811388300841897f;
    float4 qv[10];
    {
        const float* qp = q + (size_t)row * DMODEL + hd * DHEAD;
#pragma unroll
        for (int i = 0; i < 10; ++i) {
            float4 t4 = ((const float4*)qp)[i];
            qv[i] = make_float4(t4.x * scale, t4.y * scale, t4.z * scale, t4.w * scale);
        }
    }
    float s1 = -1e30f, s2 = -1e30f;
    if (l < CTXN) {
        const float* kp = kc + (size_t)l * DMODEL + hd * DHEAD;
        float s = 0.f;
#pragma unroll
        for (int i = 0; i < 10; ++i) {
            float4 kv = ((const float4*)kp)[i];
            s += qv[i].x * kv.x + qv[i].y * kv.y + qv[i].z * kv.z + qv[i].w * kv.w;
        }
        s1 = s;
    }
    if (l + 64 < CTXN) {
        const float* kp2 = kc + (size_t)(l + 64) * DMODEL + hd * DHEAD;
        float s = 0.f;
#pragma unroll
        for (int i = 0; i < 10; ++i) {
            float4 kv = ((const float4*)kp2)[i];
            s += qv[i].x * kv.x + qv[i].y * kv.y + qv[i].z * kv.z + qv[i].w * kv.w;
        }
        s2 = s;
    }
    float mx = fmaxf(s1, s2);
    for (int o = 32; o > 0; o >>= 1) mx = fmaxf(mx, __shfl_xor(mx, o));
    float p1 = (l < CTXN) ? __expf(s1 - mx) : 0.f;
    float p2 = (l + 64 < CTXN) ? __expf(s2 - mx) : 0.f;
    float ps = p1 + p2;
    for (int o = 32; o > 0; o >>= 1) ps += __shfl_xor(ps, o);
    Pl[w][l] = p1;
    Pl[w][l + 64] = p2;
    if (l < DHEAD) {
        float acc = 0.f;
        for (int j = 0; j < CTXN; ++j) acc += Pl[w][j] * vc[(size_t)j * DMODEL + hd * DHEAD + l];
        out[(size_t)row * DMODEL + hd * DHEAD + l] = acc / ps;
    }
}

// ---------------- final: out[c][p] = t0[p][c] + x[c][p] ----------------
__global__ __launch_bounds__(256) void final_k(const float* __restrict__ t0, const float* __restrict__ x,
                                               float* __restrict__ out) {
    int e = blockIdx.x * 256 + threadIdx.x;
    int c = e >> 12, p = e & 4095;
    out[e] = t0[(size_t)p * DMODEL + c] + x[e];
}

extern "C" void kernel_launch(void* const* d_in, const int* in_sizes, int n_in,
                              void* d_out, int out_size, void* d_ws, size_t ws_size,
                              hipStream_t stream) {
    const float* x      = (const float*)d_in[0];
    const float* ctx    = (const float*)d_in[1];
    const float* gn_w   = (const float*)d_in[2];
    const float* gn_b   = (const float*)d_in[3];
    const float* pin_w  = (const float*)d_in[4];
    const float* pin_b  = (const float*)d_in[5];
    const float* ln1_w  = (const float*)d_in[6];
    const float* ln1_b  = (const float*)d_in[7];
    const float* q1     = (const float*)d_in[8];
    const float* k1     = (const float*)d_in[9];
    const float* v1     = (const float*)d_in[10];
    const float* o1_w   = (const float*)d_in[11];
    const float* o1_b   = (const float*)d_in[12];
    const float* ln2_w  = (const float*)d_in[13];
    const float* ln2_b  = (const float*)d_in[14];
    const float* q2     = (const float*)d_in[15];
    const float* k2     = (const float*)d_in[16];
    const float* v2     = (const float*)d_in[17];
    const float* o2_w   = (const float*)d_in[18];
    const float* o2_b   = (const float*)d_in[19];
    const float* ln3_w  = (const float*)d_in[20];
    const float* ln3_b  = (const float*)d_in[21];
    const float* ff1_w  = (const float*)d_in[22];
    const float* ff1_b  = (const float*)d_in[23];
    const float* ff2_w  = (const float*)d_in[24];
    const float* ff2_b  = (const float*)d_in[25];
    const float* pout_w = (const float*)d_in[26];
    const float* pout_b = (const float*)d_in[27];
    float* out = (float*)d_out;

    float* ws    = (float*)d_ws;
    const size_t NB = (size_t)N_SEQ * DMODEL;   // 1310720
    float* stats = ws;
    float* h     = ws + 64;
    float* t0    = h + NB;
    float* p0    = t0 + NB;
    float* p1    = p0 + NB;
    float* p2    = p1 + NB;
    float* p3    = p2 + NB;
    float* gno   = p0;
    float* qb    = p0;
    float* kb    = p1;
    float* vb    = p2;
    float* ao    = t0;
    float* ffg   = p0;
    float* k2b   = p3;
    float* v2b   = p3 + 25600;

    // 1. GroupNorm
    gn_stats_k<<<32, 256, 0, stream>>>(x, stats);
    gn_apply_k<<<5120, 256, 0, stream>>>(x, stats, gn_w, gn_b, gno);
    // 2. proj_in: h[n,o] = sum_i gno[i][n]*pin_w[o*320+i]
    gemm_bf16_k<<<dim3(5, 64), 256, 0, stream>>>(gno, 1, 4096, pin_w, 1, 320, pin_b, nullptr, h, 4096, 320, 320, 0);
    // 3. self-attention block
    ln_k<<<4096, 64, 0, stream>>>(h, ln1_w, ln1_b, t0);
    gemm_bf16_k<<<dim3(5, 64), 256, 0, stream>>>(t0, 320, 1, q1, 320, 1, nullptr, nullptr, qb, 4096, 320, 320, 0);
    gemm_bf16_k<<<dim3(5, 64), 256, 0, stream>>>(t0, 320, 1, k1, 320, 1, nullptr, nullptr, kb, 4096, 320, 320, 0);
    gemm_bf16_k<<<dim3(5, 64), 256, 0, stream>>>(t0, 320, 1, v1, 320, 1, nullptr, nullptr, vb, 4096, 320, 320, 0);
    attn_self_mfma_k<<<dim3(64, 8), 256, 0, stream>>>(qb, kb, vb, ao);
    gemm_bf16_k<<<dim3(5, 64), 256, 0, stream>>>(ao, 320, 1, o1_w, 320, 1, o1_b, h, h, 4096, 320, 320, 0);
    // 4. cross-attention block
    ln_k<<<4096, 64, 0, stream>>>(h, ln2_w, ln2_b, t0);
    gemm_bf16_k<<<dim3(5, 64), 256, 0, stream>>>(t0, 320, 1, q2, 320, 1, nullptr, nullptr, qb, 4096, 320, 320, 0);
    gemm_bf16_k<<<dim3(5, 2), 256, 0, stream>>>(ctx, 768, 1, k2, 320, 1, nullptr, nullptr, k2b, 77, 768, 320, 0);
    gemm_bf16_k<<<dim3(5, 2), 256, 0, stream>>>(ctx, 768, 1, v2, 320, 1, nullptr, nullptr, v2b, 77, 768, 320, 0);
    attn_cross_k<<<8192, 256, 0, stream>>>(qb, k2b, v2b, ao);
    gemm_bf16_k<<<dim3(5, 64), 256, 0, stream>>>(ao, 320, 1, o2_w, 320, 1, o2_b, h, h, 4096, 320, 320, 0);
    // 5. GEGLU FF
    ln_k<<<4096, 64, 0, stream>>>(h, ln3_w, ln3_b, t0);
    gemm_bf16_k<<<dim3(20, 64), 256, 0, stream>>>(t0, 320, 1, ff1_w, 2560, 1, ff1_b, nullptr, ffg, 4096, 320, 1280, 1280);
    gemm_bf16_k<<<dim3(5, 64), 256, 0, stream>>>(ffg, 1280, 1, ff2_w, 320, 1, ff2_b, h, h, 4096, 1280, 320, 0);
    // 6. proj_out + input residual
    gemm_bf16_k<<<dim3(5, 64), 256, 0, stream>>>(h, 320, 1, pout_w, 1, 320, pout_b, nullptr, t0, 4096, 320, 320, 0);
    final_k<<<5120, 256, 0, stream>>>(t0, x, out);
}

// Round 5
// 637.791 us; speedup vs baseline: 8.4192x; 1.3000x over previous
//
#include <hip/hip_runtime.h>
#include <hip/hip_bf16.h>
#include <math.h>

#define N_SEQ  4096
#define DMODEL 320
#define NHEADS 8
#define DHEAD  40
#define CTXN   77
#define CTXD   768
#define FFI    1280

typedef short s8v __attribute__((ext_vector_type(8)));
typedef float f4v __attribute__((ext_vector_type(4)));
typedef unsigned short u16;

static __device__ __forceinline__ u16 bf16u(float x) {           // RNE
    unsigned u = __float_as_uint(x);
    return (u16)((u + 0x7FFFu + ((u >> 16) & 1u)) >> 16);
}
static __device__ __forceinline__ float b2f(u16 v) { return __uint_as_float((unsigned)v << 16); }
static __device__ __forceinline__ unsigned pack2(float a, float b) {
    return (unsigned)bf16u(a) | ((unsigned)bf16u(b) << 16);
}

// ---------------- weight pre-convert: dst[o*K+k] = bf16(src), src [K][O] (trans) or [O][K] ----------------
struct WC { const float* s; u16* d; int K, O, trans; };
struct WCs { WC a[12]; };
__global__ __launch_bounds__(256) void wcast_k(WCs P) {
    WC w = P.a[blockIdx.y];
    int e = blockIdx.x * 256 + threadIdx.x;
    if (e >= w.K * w.O) return;
    int o = e / w.K, k = e - o * w.K;
    float v = w.trans ? w.s[(size_t)k * w.O + o] : w.s[e];
    w.d[e] = bf16u(v);
}

// ---------------- GroupNorm ----------------
__global__ __launch_bounds__(256) void gn_stats_k(const float* __restrict__ x, float* __restrict__ stats) {
    __shared__ float red[512];
    int g = blockIdx.x, t = threadIdx.x;
    const float* xp = x + (size_t)g * 40960;
    float s = 0.f, ss = 0.f;
    for (int i = t; i < 40960; i += 256) { float v = xp[i]; s += v; ss += v * v; }
    red[t] = s; red[256 + t] = ss;
    __syncthreads();
    for (int st = 128; st > 0; st >>= 1) {
        if (t < st) { red[t] += red[t + st]; red[256 + t] += red[256 + t + st]; }
        __syncthreads();
    }
    if (t == 0) {
        float mean = red[0] / 40960.f;
        float var  = red[256] / 40960.f - mean * mean;
        stats[2 * g] = mean;
        stats[2 * g + 1] = rsqrtf(var + 1e-6f);
    }
}

__global__ __launch_bounds__(256) void gn_apply_k(const float* __restrict__ x, const float* __restrict__ stats,
                                                  const float* __restrict__ gw, const float* __restrict__ gb,
                                                  float* __restrict__ out) {
    int e = blockIdx.x * 256 + threadIdx.x;
    int c = e >> 12;
    int g = c / 10;
    out[e] = (x[e] - stats[2 * g]) * stats[2 * g + 1] * gw[c] + gb[c];
}

// ---------------- LayerNorm, bf16 out ----------------
__global__ __launch_bounds__(64) void ln_b16_k(const float* __restrict__ in, const float* __restrict__ w,
                                               const float* __restrict__ b, u16* __restrict__ out) {
    int row = blockIdx.x, l = threadIdx.x;
    const float* p = in + (size_t)row * DMODEL;
    float xv[5], s = 0.f, ss = 0.f;
#pragma unroll
    for (int j = 0; j < 5; ++j) { xv[j] = p[l + 64 * j]; s += xv[j]; ss += xv[j] * xv[j]; }
    for (int o = 32; o > 0; o >>= 1) { s += __shfl_xor(s, o); ss += __shfl_xor(ss, o); }
    float mean = s * (1.f / 320.f);
    float var  = ss * (1.f / 320.f) - mean * mean;
    float rstd = rsqrtf(var + 1e-5f);
    u16* q = out + (size_t)row * DMODEL;
#pragma unroll
    for (int j = 0; j < 5; ++j) {
        int i = l + 64 * j;
        q[i] = bf16u((xv[j] - mean) * rstd * w[i] + b[i]);
    }
}

// ---------------- bf16 MFMA GEMM v2 ----------------
// out[n,o] = sum_k A[n][k] * Wt[o][k] (+bias)(+GEGLU)(+res). Wt pre-converted bf16 [O][K].
// A modes: 0 = bf16 row-major, 1 = f32 row-major, 2 = f32 col-major (A[k*lda+n]).
// blockIdx.z selects GArg (fused multi-output GEMMs sharing A).
struct GArg { const u16* Wt; const float* bias; float* outf; u16* outb; int ob_mode; };  // ob: 1 row-major, 2 transposed
#define GP 72
__global__ __launch_bounds__(256) void gemm_v2(const void* __restrict__ Av, int a_mode, int lda,
                                               GArg g0, GArg g1, GArg g2,
                                               const float* __restrict__ res,
                                               int Mrows, int K, int Oout, int geglu_off, int obT_stride) {
    __shared__ __align__(16) u16 As[64 * GP];
    __shared__ __align__(16) u16 Wsm[64 * GP];
    __shared__ __align__(16) u16 Wgm[64 * GP];
    const int t = threadIdx.x;
    const int w = t >> 6, lane = t & 63, c = lane & 15, quad = lane >> 4;
    const int o0 = blockIdx.x * 64, n0 = blockIdx.y * 64;
    GArg g = (blockIdx.z == 0) ? g0 : ((blockIdx.z == 1) ? g1 : g2);
    const bool geglu = (geglu_off > 0);
    const f4v zero = {0.f, 0.f, 0.f, 0.f};
    f4v acc[4]  = {zero, zero, zero, zero};
    f4v accg[4] = {zero, zero, zero, zero};
    const s8v z8 = {0, 0, 0, 0, 0, 0, 0, 0};

    for (int k0 = 0; k0 < K; k0 += 64) {
        __syncthreads();
        if (a_mode == 0) {              // bf16 row-major
            const u16* A = (const u16*)Av;
#pragma unroll
            for (int i = t; i < 512; i += 256) {
                int r = i >> 3, sg = i & 7;
                int n = n0 + r;
                *(s8v*)&As[r * GP + sg * 8] =
                    (n < Mrows) ? *(const s8v*)(A + (size_t)n * lda + k0 + sg * 8) : z8;
            }
        } else if (a_mode == 1) {       // f32 row-major
            const float* A = (const float*)Av;
            int r = t >> 2, s16 = (t & 3) * 16;
            int n = n0 + r;
            unsigned* dst = (unsigned*)&As[r * GP + s16];
            if (n < Mrows) {
                const float* src = A + (size_t)n * lda + k0 + s16;
#pragma unroll
                for (int i = 0; i < 8; ++i) dst[i] = pack2(src[2 * i], src[2 * i + 1]);
            } else {
#pragma unroll
                for (int i = 0; i < 8; ++i) dst[i] = 0u;
            }
        } else {                        // f32 col-major
            const float* A = (const float*)Av;
#pragma unroll
            for (int j = 0; j < 16; ++j) {
                int e = t + 256 * j; int nn = e & 63, kk = e >> 6;
                int n = n0 + nn;
                As[nn * GP + kk] = (n < Mrows) ? bf16u(A[(size_t)(k0 + kk) * lda + n]) : (u16)0;
            }
        }
#pragma unroll
        for (int i = t; i < 512; i += 256) {
            int oo = i >> 3, sg = i & 7;
            *(s8v*)&Wsm[oo * GP + sg * 8] = *(const s8v*)(g.Wt + (size_t)(o0 + oo) * K + k0 + sg * 8);
        }
        if (geglu) {
#pragma unroll
            for (int i = t; i < 512; i += 256) {
                int oo = i >> 3, sg = i & 7;
                *(s8v*)&Wgm[oo * GP + sg * 8] = *(const s8v*)(g.Wt + (size_t)(o0 + oo + geglu_off) * K + k0 + sg * 8);
            }
        }
        __syncthreads();
        s8v a0 = *(const s8v*)&As[(w * 16 + c) * GP + quad * 8];
        s8v a1 = *(const s8v*)&As[(w * 16 + c) * GP + 32 + quad * 8];
#pragma unroll
        for (int nt = 0; nt < 4; ++nt) {
            s8v b0 = *(const s8v*)&Wsm[(nt * 16 + c) * GP + quad * 8];
            s8v b1 = *(const s8v*)&Wsm[(nt * 16 + c) * GP + 32 + quad * 8];
            acc[nt] = __builtin_amdgcn_mfma_f32_16x16x32_bf16(a0, b0, acc[nt], 0, 0, 0);
            acc[nt] = __builtin_amdgcn_mfma_f32_16x16x32_bf16(a1, b1, acc[nt], 0, 0, 0);
            if (geglu) {
                s8v q0 = *(const s8v*)&Wgm[(nt * 16 + c) * GP + quad * 8];
                s8v q1 = *(const s8v*)&Wgm[(nt * 16 + c) * GP + 32 + quad * 8];
                accg[nt] = __builtin_amdgcn_mfma_f32_16x16x32_bf16(a0, q0, accg[nt], 0, 0, 0);
                accg[nt] = __builtin_amdgcn_mfma_f32_16x16x32_bf16(a1, q1, accg[nt], 0, 0, 0);
            }
        }
    }
#pragma unroll
    for (int nt = 0; nt < 4; ++nt) {
#pragma unroll
        for (int r = 0; r < 4; ++r) {
            int n = n0 + w * 16 + quad * 4 + r;
            if (n >= Mrows) continue;
            int o = o0 + nt * 16 + c;
            float v = acc[nt][r] + (g.bias ? g.bias[o] : 0.f);
            if (geglu) {
                float gg = accg[nt][r] + g.bias[o + geglu_off];
                v = v * 0.5f * gg * (1.f + erff(gg * 0.70710678118654752f));
            }
            if (res) v += res[(size_t)n * Oout + o];
            if (g.outf) g.outf[(size_t)n * Oout + o] = v;
            if (g.ob_mode == 1) g.outb[(size_t)n * Oout + o] = bf16u(v);
            else if (g.ob_mode == 2) g.outb[(size_t)o * obT_stride + n] = bf16u(v);
        }
    }
}

// ---------------- Self-attention v3: bf16 in (q,k row-major; v transposed), fixed-max softmax ----------------
// grid (64 qtiles, 8 heads), 256 thr = 4 waves; 128-key tiles.
#define KP 72    // Ks pitch
#define VP 136   // Vs/Ps pitch (128 keys + 8 pad)
__global__ __launch_bounds__(256) void attn_self3_k(const u16* __restrict__ qb, const u16* __restrict__ kb,
                                                    const u16* __restrict__ vt, u16* __restrict__ out) {
    __shared__ __align__(16) u16 Ks[128 * KP];
    __shared__ __align__(16) u16 Vs[48 * VP];
    __shared__ __align__(16) u16 Ps[64 * VP];
    const int t = threadIdx.x;
    const int w = t >> 6, lane = t & 63, c = lane & 15, quad = lane >> 4;
    const int hd = blockIdx.y;
    const int q0 = blockIdx.x * 64;
    const float SCALE = 0.15811388300841897f;   // 1/sqrt(40)
    const f4v zero = {0.f, 0.f, 0.f, 0.f};
    const s8v z8 = {0, 0, 0, 0, 0, 0, 0, 0};

    // zero pads once (K dims 40..63, V rows 40..47)
    for (int i = t; i < 128 * KP / 2; i += 256) ((unsigned*)Ks)[i] = 0u;
    for (int i = t; i < 48 * VP / 2; i += 256) ((unsigned*)Vs)[i] = 0u;

    // Q A-fragments direct from global
    const u16* qrow = qb + (size_t)(q0 + w * 16 + c) * DMODEL + hd * DHEAD;
    s8v qa0 = *(const s8v*)(qrow + quad * 8);
    s8v qa1 = z8;
    if (quad == 0) qa1 = *(const s8v*)(qrow + 32);

    float lacc[4] = {0.f, 0.f, 0.f, 0.f};
    f4v o0 = zero, o1 = zero, o2 = zero;
    __syncthreads();   // pads visible

    for (int kt = 0; kt < 32; ++kt) {
        const int k0 = kt * 128;
        __syncthreads();
        for (int i = t; i < 640; i += 256) {           // K: 128 rows x 5 segs (40 dims)
            int r = i / 5, sg = i - r * 5;
            *(s8v*)&Ks[r * KP + sg * 8] = *(const s8v*)(kb + (size_t)(k0 + r) * DMODEL + hd * DHEAD + sg * 8);
        }
        for (int i = t; i < 640; i += 256) {           // V^T: 40 dims x 16 segs (128 keys)
            int d = i >> 4, sg = i & 15;
            *(s8v*)&Vs[d * VP + sg * 8] = *(const s8v*)(vt + (size_t)(hd * DHEAD + d) * N_SEQ + k0 + sg * 8);
        }
        __syncthreads();

        // S = Q K^T : 16 q-rows x 128 keys per wave
        f4v sarr[8];
#pragma unroll
        for (int h2 = 0; h2 < 2; ++h2)
#pragma unroll
            for (int nt = 0; nt < 4; ++nt) {
                const int kr = h2 * 64 + nt * 16 + c;
                s8v b0 = *(const s8v*)&Ks[kr * KP + quad * 8];
                s8v b1 = *(const s8v*)&Ks[kr * KP + 32 + quad * 8];
                f4v s = __builtin_amdgcn_mfma_f32_16x16x32_bf16(qa0, b0, zero, 0, 0, 0);
                s = __builtin_amdgcn_mfma_f32_16x16x32_bf16(qa1, b1, s, 0, 0, 0);
                sarr[h2 * 4 + nt] = s;
            }

        // fixed-max softmax numerators (logits |s*scale| << 1, exp safe)
#pragma unroll
        for (int reg = 0; reg < 8; ++reg) {
            int colb = (reg >> 2) * 64 + (reg & 3) * 16 + c;
#pragma unroll
            for (int r = 0; r < 4; ++r) {
                float pv = __expf(sarr[reg][r] * SCALE);
                lacc[r] += pv;
                Ps[(w * 16 + quad * 4 + r) * VP + colb] = (u16)((__float_as_uint(pv) + 0x8000u) >> 16);
            }
        }

        // O += P V (P via LDS to A-layout; same wave wrote the rows it reads)
#pragma unroll
        for (int h2 = 0; h2 < 2; ++h2) {
            s8v pa0 = *(const s8v*)&Ps[(w * 16 + c) * VP + h2 * 64 + quad * 8];
            s8v pa1 = *(const s8v*)&Ps[(w * 16 + c) * VP + h2 * 64 + 32 + quad * 8];
            {
                s8v v0 = *(const s8v*)&Vs[(0 * 16 + c) * VP + h2 * 64 + quad * 8];
                s8v v1 = *(const s8v*)&Vs[(0 * 16 + c) * VP + h2 * 64 + 32 + quad * 8];
                o0 = __builtin_amdgcn_mfma_f32_16x16x32_bf16(pa0, v0, o0, 0, 0, 0);
                o0 = __builtin_amdgcn_mfma_f32_16x16x32_bf16(pa1, v1, o0, 0, 0, 0);
            }
            {
                s8v v0 = *(const s8v*)&Vs[(1 * 16 + c) * VP + h2 * 64 + quad * 8];
                s8v v1 = *(const s8v*)&Vs[(1 * 16 + c) * VP + h2 * 64 + 32 + quad * 8];
                o1 = __builtin_amdgcn_mfma_f32_16x16x32_bf16(pa0, v0, o1, 0, 0, 0);
                o1 = __builtin_amdgcn_mfma_f32_16x16x32_bf16(pa1, v1, o1, 0, 0, 0);
            }
            {
                s8v v0 = *(const s8v*)&Vs[(2 * 16 + c) * VP + h2 * 64 + quad * 8];
                s8v v1 = *(const s8v*)&Vs[(2 * 16 + c) * VP + h2 * 64 + 32 + quad * 8];
                o2 = __builtin_amdgcn_mfma_f32_16x16x32_bf16(pa0, v0, o2, 0, 0, 0);
                o2 = __builtin_amdgcn_mfma_f32_16x16x32_bf16(pa1, v1, o2, 0, 0, 0);
            }
        }
    }

    // reduce l within each 16-lane row group, store bf16
#pragma unroll
    for (int r = 0; r < 4; ++r) {
        float l = lacc[r];
        l += __shfl_xor(l, 1); l += __shfl_xor(l, 2); l += __shfl_xor(l, 4); l += __shfl_xor(l, 8);
        float inv = 1.f / l;
        const size_t row = (size_t)(q0 + w * 16 + quad * 4 + r) * DMODEL + hd * DHEAD;
        out[row + c]      = bf16u(o0[r] * inv);
        out[row + 16 + c] = bf16u(o1[r] * inv);
        if (c < 8) out[row + 32 + c] = bf16u(o2[r] * inv);
    }
}

// ---------------- Cross-attention (M=77): one wave per (row, head); q bf16, k/v f32 ----------------
__global__ __launch_bounds__(256) void attn_cross2_k(const u16* __restrict__ q, const float* __restrict__ kc,
                                                     const float* __restrict__ vc, u16* __restrict__ out) {
    __shared__ float Pl[4][128];
    const int t = threadIdx.x, w = t >> 6, l = t & 63;
    const int gw = blockIdx.x * 4 + w;
    const int row = gw >> 3, hd = gw & 7;
    const float scale = 0.15811388300841897f;
    float qv[40];
    {
        const u16* qp = q + (size_t)row * DMODEL + hd * DHEAD;
#pragma unroll
        for (int i = 0; i < 5; ++i) {
            s8v v8 = *(const s8v*)(qp + i * 8);
#pragma unroll
            for (int j = 0; j < 8; ++j) qv[i * 8 + j] = b2f((u16)v8[j]) * scale;
        }
    }
    float s1 = -1e30f, s2 = -1e30f;
    if (l < CTXN) {
        const float* kp = kc + (size_t)l * DMODEL + hd * DHEAD;
        float s = 0.f;
#pragma unroll
        for (int i = 0; i < 40; ++i) s += qv[i] * kp[i];
        s1 = s;
    }
    if (l + 64 < CTXN) {
        const float* kp = kc + (size_t)(l + 64) * DMODEL + hd * DHEAD;
        float s = 0.f;
#pragma unroll
        for (int i = 0; i < 40; ++i) s += qv[i] * kp[i];
        s2 = s;
    }
    float mx = fmaxf(s1, s2);
    for (int o = 32; o > 0; o >>= 1) mx = fmaxf(mx, __shfl_xor(mx, o));
    float p1 = (l < CTXN) ? __expf(s1 - mx) : 0.f;
    float p2 = (l + 64 < CTXN) ? __expf(s2 - mx) : 0.f;
    float ps = p1 + p2;
    for (int o = 32; o > 0; o >>= 1) ps += __shfl_xor(ps, o);
    Pl[w][l] = p1;
    Pl[w][l + 64] = p2;
    if (l < DHEAD) {
        float acc = 0.f;
        for (int j = 0; j < CTXN; ++j) acc += Pl[w][j] * vc[(size_t)j * DMODEL + hd * DHEAD + l];
        out[(size_t)row * DMODEL + hd * DHEAD + l] = bf16u(acc / ps);
    }
}

// ---------------- final: out[c][p] = t0[p][c] + x[c][p] ----------------
__global__ __launch_bounds__(256) void final_k(const float* __restrict__ t0, const float* __restrict__ x,
                                               float* __restrict__ out) {
    int e = blockIdx.x * 256 + threadIdx.x;
    int c = e >> 12, p = e & 4095;
    out[e] = t0[(size_t)p * DMODEL + c] + x[e];
}

extern "C" void kernel_launch(void* const* d_in, const int* in_sizes, int n_in,
                              void* d_out, int out_size, void* d_ws, size_t ws_size,
                              hipStream_t stream) {
    const float* x      = (const float*)d_in[0];
    const float* ctx    = (const float*)d_in[1];
    const float* gn_w   = (const float*)d_in[2];
    const float* gn_b   = (const float*)d_in[3];
    const float* pin_w  = (const float*)d_in[4];
    const float* pin_b  = (const float*)d_in[5];
    const float* ln1_w  = (const float*)d_in[6];
    const float* ln1_b  = (const float*)d_in[7];
    const float* q1     = (const float*)d_in[8];
    const float* k1     = (const float*)d_in[9];
    const float* v1     = (const float*)d_in[10];
    const float* o1_w   = (const float*)d_in[11];
    const float* o1_b   = (const float*)d_in[12];
    const float* ln2_w  = (const float*)d_in[13];
    const float* ln2_b  = (const float*)d_in[14];
    const float* q2     = (const float*)d_in[15];
    const float* k2     = (const float*)d_in[16];
    const float* v2     = (const float*)d_in[17];
    const float* o2_w   = (const float*)d_in[18];
    const float* o2_b   = (const float*)d_in[19];
    const float* ln3_w  = (const float*)d_in[20];
    const float* ln3_b  = (const float*)d_in[21];
    const float* ff1_w  = (const float*)d_in[22];
    const float* ff1_b  = (const float*)d_in[23];
    const float* ff2_w  = (const float*)d_in[24];
    const float* ff2_b  = (const float*)d_in[25];
    const float* pout_w = (const float*)d_in[26];
    const float* pout_b = (const float*)d_in[27];
    float* out = (float*)d_out;

    char* base = (char*)d_ws;
    float* h     = (float*)(base);                       // f32 [4096][320]
    char*  regA  = base + 5242880;                       // gno f32 | ffg16 (spans A+B+C) | t0f
    u16*   qb16  = (u16*)(base + 10485760);
    u16*   kb16  = (u16*)(base + 13107200);
    u16*   vt16  = (u16*)(base + 15728640);              // [320][4096]
    u16*   t0b   = (u16*)(base + 18350080);              // LN out / attn out (aliased)
    float* stats = (float*)(base + 20971520);
    float* k2f   = (float*)(base + 20972544);
    float* v2f   = (float*)(base + 21075)                ;
    v2f          = (float*)(base + 21074944);
    u16*   wbase = (u16*)(base + 21177344);
    u16* pinT  = wbase;                  // 102400
    u16* q1T   = pinT  + 102400;
    u16* k1T   = q1T   + 102400;
    u16* v1T   = k1T   + 102400;
    u16* o1T   = v1T   + 102400;
    u16* q2T   = o1T   + 102400;
    u16* o2T   = q2T   + 102400;
    u16* k2T   = o2T   + 102400;         // 245760
    u16* v2T   = k2T   + 245760;
    u16* ff1T  = v2T   + 245760;         // 819200
    u16* ff2T  = ff1T  + 819200;         // 409600
    u16* poutT = ff2T  + 409600;         // 102400
    float* gno  = (float*)regA;
    u16*   ffg16 = (u16*)regA;           // [2048][1280] per chunk
    float* t0f  = (float*)regA;
    u16*   ao16 = t0b;

    // 0. convert all weights to bf16 [O][K]
    WCs wd;
    wd.a[0]  = {pin_w,  pinT,  320,  320,  0};
    wd.a[1]  = {q1,     q1T,   320,  320,  1};
    wd.a[2]  = {k1,     k1T,   320,  320,  1};
    wd.a[3]  = {v1,     v1T,   320,  320,  1};
    wd.a[4]  = {o1_w,   o1T,   320,  320,  1};
    wd.a[5]  = {q2,     q2T,   320,  320,  1};
    wd.a[6]  = {o2_w,   o2T,   320,  320,  1};
    wd.a[7]  = {k2,     k2T,   768,  320,  1};
    wd.a[8]  = {v2,     v2T,   768,  320,  1};
    wd.a[9]  = {ff1_w,  ff1T,  320,  2560, 1};
    wd.a[10] = {ff2_w,  ff2T,  1280, 320,  1};
    wd.a[11] = {pout_w, poutT, 320,  320,  0};
    wcast_k<<<dim3(3200, 12), 256, 0, stream>>>(wd);

    GArg gz = {nullptr, nullptr, nullptr, nullptr, 0};

    // 1. GroupNorm
    gn_stats_k<<<32, 256, 0, stream>>>(x, stats);
    gn_apply_k<<<5120, 256, 0, stream>>>(x, stats, gn_w, gn_b, gno);
    // 2. proj_in: A col-major f32
    {
        GArg g0 = {pinT, pin_b, h, nullptr, 0};
        gemm_v2<<<dim3(5, 64, 1), 256, 0, stream>>>(gno, 2, 4096, g0, gz, gz, nullptr, 4096, 320, 320, 0, 0);
    }
    // 3. self-attention block
    ln_b16_k<<<4096, 64, 0, stream>>>(h, ln1_w, ln1_b, t0b);
    {
        GArg g0 = {q1T, nullptr, nullptr, qb16, 1};
        GArg g1 = {k1T, nullptr, nullptr, kb16, 1};
        GArg g2 = {v1T, nullptr, nullptr, vt16, 2};
        gemm_v2<<<dim3(5, 64, 3), 256, 0, stream>>>(t0b, 0, 320, g0, g1, g2, nullptr, 4096, 320, 320, 0, 4096);
    }
    attn_self3_k<<<dim3(64, 8), 256, 0, stream>>>(qb16, kb16, vt16, ao16);
    {
        GArg g0 = {o1T, o1_b, h, nullptr, 0};
        gemm_v2<<<dim3(5, 64, 1), 256, 0, stream>>>(ao16, 0, 320, g0, gz, gz, h, 4096, 320, 320, 0, 0);
    }
    // 4. cross-attention block
    ln_b16_k<<<4096, 64, 0, stream>>>(h, ln2_w, ln2_b, t0b);
    {
        GArg g0 = {q2T, nullptr, nullptr, qb16, 1};
        gemm_v2<<<dim3(5, 64, 1), 256, 0, stream>>>(t0b, 0, 320, g0, gz, gz, nullptr, 4096, 320, 320, 0, 0);
    }
    {
        GArg g0 = {k2T, nullptr, k2f, nullptr, 0};
        GArg g1 = {v2T, nullptr, v2f, nullptr, 0};
        gemm_v2<<<dim3(5, 2, 2), 256, 0, stream>>>(ctx, 1, 768, g0, g1, gz, nullptr, 77, 768, 320, 0, 0);
    }
    attn_cross2_k<<<8192, 256, 0, stream>>>(qb16, k2f, v2f, ao16);
    {
        GArg g0 = {o2T, o2_b, h, nullptr, 0};
        gemm_v2<<<dim3(5, 64, 1), 256, 0, stream>>>(ao16, 0, 320, g0, gz, gz, h, 4096, 320, 320, 0, 0);
    }
    // 5. GEGLU FF in two row-chunks (ffg16 aliases gno/qb/kb region)
    ln_b16_k<<<4096, 64, 0, stream>>>(h, ln3_w, ln3_b, t0b);
    for (int cch = 0; cch < 2; ++cch) {
        {
            GArg g0 = {ff1T, ff1_b, nullptr, ffg16, 1};
            gemm_v2<<<dim3(20, 32, 1), 256, 0, stream>>>(t0b + (size_t)cch * 2048 * 320, 0, 320,
                                                         g0, gz, gz, nullptr, 2048, 320, 1280, 1280, 0);
        }
        {
            GArg g0 = {ff2T, ff2_b, h + (size_t)cch * 2048 * 320, nullptr, 0};
            gemm_v2<<<dim3(5, 32, 1), 256, 0, stream>>>(ffg16, 0, 1280, g0, gz, gz,
                                                        h + (size_t)cch * 2048 * 320, 2048, 1280, 320, 0, 0);
        }
    }
    // 6. proj_out + input residual
    {
        GArg g0 = {poutT, pout_b, t0f, nullptr, 0};
        gemm_v2<<<dim3(5, 64, 1), 256, 0, stream>>>(h, 1, 320, g0, gz, gz, nullptr, 4096, 320, 320, 0, 0);
    }
    final_k<<<5120, 256, 0, stream>>>(t0f, x, out);
}

// Round 6
// 623.045 us; speedup vs baseline: 8.6184x; 1.0237x over previous
//
#include <hip/hip_runtime.h>
#include <hip/hip_bf16.h>
#include <math.h>

#define N_SEQ  4096
#define DMODEL 320
#define NHEADS 8
#define DHEAD  40
#define CTXN   77
#define CTXD   768
#define FFI    1280

typedef short s8v __attribute__((ext_vector_type(8)));
typedef float f4v __attribute__((ext_vector_type(4)));
typedef unsigned short u16;

static __device__ __forceinline__ u16 bf16u(float x) {           // RNE
    unsigned u = __float_as_uint(x);
    return (u16)((u + 0x7FFFu + ((u >> 16) & 1u)) >> 16);
}
static __device__ __forceinline__ float b2f(u16 v) { return __uint_as_float((unsigned)v << 16); }
static __device__ __forceinline__ unsigned pack2(float a, float b) {
    return (unsigned)bf16u(a) | ((unsigned)bf16u(b) << 16);
}

// ---------------- weight pre-convert: dst[o*K+k] = bf16(src), src [K][O] (trans) or [O][K] ----------------
struct WC { const float* s; u16* d; int K, O, trans; };
struct WCs { WC a[12]; };
__global__ __launch_bounds__(256) void wcast_k(WCs P) {
    WC w = P.a[blockIdx.y];
    int e = blockIdx.x * 256 + threadIdx.x;
    if (e >= w.K * w.O) return;
    int o = e / w.K, k = e - o * w.K;
    float v = w.trans ? w.s[(size_t)k * w.O + o] : w.s[e];
    w.d[e] = bf16u(v);
}

// ---------------- GroupNorm stats -> per-channel scale/shift ----------------
__global__ __launch_bounds__(256) void gn_stats_k(const float* __restrict__ x,
                                                  const float* __restrict__ gw, const float* __restrict__ gb,
                                                  float* __restrict__ sc, float* __restrict__ sh) {
    __shared__ float red[512];
    __shared__ float ms[2];
    int g = blockIdx.x, t = threadIdx.x;
    const float* xp = x + (size_t)g * 40960;
    float s = 0.f, ss = 0.f;
    for (int i = t; i < 40960; i += 256) { float v = xp[i]; s += v; ss += v * v; }
    red[t] = s; red[256 + t] = ss;
    __syncthreads();
    for (int st = 128; st > 0; st >>= 1) {
        if (t < st) { red[t] += red[t + st]; red[256 + t] += red[256 + t + st]; }
        __syncthreads();
    }
    if (t == 0) {
        float mean = red[0] / 40960.f;
        float var  = red[256] / 40960.f - mean * mean;
        ms[0] = mean; ms[1] = rsqrtf(var + 1e-6f);
    }
    __syncthreads();
    if (t < 10) {
        int c = g * 10 + t;
        float rstd = ms[1], mean = ms[0];
        float scv = gw[c] * rstd;
        sc[c] = scv;
        sh[c] = gb[c] - mean * scv;
    }
}

// ---------------- LayerNorm stats (mu, 1/sigma per row) ----------------
__global__ __launch_bounds__(256) void ln_stats_k(const float* __restrict__ in,
                                                  float* __restrict__ mu, float* __restrict__ rs) {
    int row = blockIdx.x * 4 + (threadIdx.x >> 6), l = threadIdx.x & 63;
    const float* p = in + (size_t)row * DMODEL;
    float s = 0.f, ss = 0.f;
#pragma unroll
    for (int j = 0; j < 5; ++j) { float v = p[l + 64 * j]; s += v; ss += v * v; }
    for (int o = 32; o > 0; o >>= 1) { s += __shfl_xor(s, o); ss += __shfl_xor(ss, o); }
    if (l == 0) {
        float mean = s * (1.f / 320.f);
        float var  = ss * (1.f / 320.f) - mean * mean;
        mu[row] = mean;
        rs[row] = rsqrtf(var + 1e-5f);
    }
}

// ---------------- bf16 MFMA GEMM v3 (fused norm staging, fused epilogues) ----------------
// A modes: 0 bf16 row-major | 1 f32 row-major | 2 f32 col-major w/ cw[k]*x+cb[k] (GN)
//          3 f32 row-major w/ ((x-mu[n])*rs[n])*cw[k]+cb[k] (LN)
// ob_mode: 0 none | 1 outb row-major bf16 | 2 outb transposed bf16 | 3 outf transposed f32 + res[o][n]
struct GArg { const u16* Wt; const float* bias; float* outf; u16* outb; int ob_mode; };
#define GP 72
__global__ __launch_bounds__(256) void gemm_v3(const void* __restrict__ Av, int a_mode, int lda,
                                               const float* __restrict__ mu, const float* __restrict__ rs,
                                               const float* __restrict__ cw, const float* __restrict__ cb,
                                               GArg g0, GArg g1, GArg g2,
                                               const float* __restrict__ res,
                                               int Mrows, int K, int Oout, int geglu_off, int obT_stride) {
    __shared__ __align__(16) u16 As[64 * GP];
    __shared__ __align__(16) u16 Wsm[64 * GP];
    __shared__ __align__(16) u16 Wgm[64 * GP];
    const int t = threadIdx.x;
    const int w = t >> 6, lane = t & 63, c = lane & 15, quad = lane >> 4;
    const int o0 = blockIdx.x * 64, n0 = blockIdx.y * 64;
    GArg g = (blockIdx.z == 0) ? g0 : ((blockIdx.z == 1) ? g1 : g2);
    const bool geglu = (geglu_off > 0);
    const f4v zero = {0.f, 0.f, 0.f, 0.f};
    f4v acc[4]  = {zero, zero, zero, zero};
    f4v accg[4] = {zero, zero, zero, zero};
    const s8v z8 = {0, 0, 0, 0, 0, 0, 0, 0};

    for (int k0 = 0; k0 < K; k0 += 64) {
        __syncthreads();
        if (a_mode == 0) {
            const u16* A = (const u16*)Av;
#pragma unroll
            for (int i = t; i < 512; i += 256) {
                int r = i >> 3, sg = i & 7;
                int n = n0 + r;
                *(s8v*)&As[r * GP + sg * 8] =
                    (n < Mrows) ? *(const s8v*)(A + (size_t)n * lda + k0 + sg * 8) : z8;
            }
        } else if (a_mode == 1) {
            const float* A = (const float*)Av;
            int r = t >> 2, s16 = (t & 3) * 16;
            int n = n0 + r;
            unsigned* dst = (unsigned*)&As[r * GP + s16];
            if (n < Mrows) {
                const float* src = A + (size_t)n * lda + k0 + s16;
#pragma unroll
                for (int i = 0; i < 8; ++i) dst[i] = pack2(src[2 * i], src[2 * i + 1]);
            } else {
#pragma unroll
                for (int i = 0; i < 8; ++i) dst[i] = 0u;
            }
        } else if (a_mode == 2) {
            const float* A = (const float*)Av;
#pragma unroll
            for (int j = 0; j < 16; ++j) {
                int e = t + 256 * j; int nn = e & 63, kk = e >> 6;
                int n = n0 + nn, kgl = k0 + kk;
                As[nn * GP + kk] = (n < Mrows) ? bf16u(A[(size_t)kgl * lda + n] * cw[kgl] + cb[kgl]) : (u16)0;
            }
        } else {   // 3: LN-fused f32 row-major
            const float* A = (const float*)Av;
            int r = t >> 2, s16 = (t & 3) * 16;
            int n = n0 + r;
            unsigned* dst = (unsigned*)&As[r * GP + s16];
            if (n < Mrows) {
                const float* src = A + (size_t)n * lda + k0 + s16;
                const float* cwp = cw + k0 + s16;
                const float* cbp = cb + k0 + s16;
                float m_ = mu[n], rr = rs[n];
#pragma unroll
                for (int i = 0; i < 8; ++i) {
                    float a0 = (src[2 * i]     - m_) * rr * cwp[2 * i]     + cbp[2 * i];
                    float a1 = (src[2 * i + 1] - m_) * rr * cwp[2 * i + 1] + cbp[2 * i + 1];
                    dst[i] = pack2(a0, a1);
                }
            } else {
#pragma unroll
                for (int i = 0; i < 8; ++i) dst[i] = 0u;
            }
        }
#pragma unroll
        for (int i = t; i < 512; i += 256) {
            int oo = i >> 3, sg = i & 7;
            *(s8v*)&Wsm[oo * GP + sg * 8] = *(const s8v*)(g.Wt + (size_t)(o0 + oo) * K + k0 + sg * 8);
        }
        if (geglu) {
#pragma unroll
            for (int i = t; i < 512; i += 256) {
                int oo = i >> 3, sg = i & 7;
                *(s8v*)&Wgm[oo * GP + sg * 8] = *(const s8v*)(g.Wt + (size_t)(o0 + oo + geglu_off) * K + k0 + sg * 8);
            }
        }
        __syncthreads();
        s8v a0 = *(const s8v*)&As[(w * 16 + c) * GP + quad * 8];
        s8v a1 = *(const s8v*)&As[(w * 16 + c) * GP + 32 + quad * 8];
#pragma unroll
        for (int nt = 0; nt < 4; ++nt) {
            s8v b0 = *(const s8v*)&Wsm[(nt * 16 + c) * GP + quad * 8];
            s8v b1 = *(const s8v*)&Wsm[(nt * 16 + c) * GP + 32 + quad * 8];
            acc[nt] = __builtin_amdgcn_mfma_f32_16x16x32_bf16(a0, b0, acc[nt], 0, 0, 0);
            acc[nt] = __builtin_amdgcn_mfma_f32_16x16x32_bf16(a1, b1, acc[nt], 0, 0, 0);
            if (geglu) {
                s8v q0 = *(const s8v*)&Wgm[(nt * 16 + c) * GP + quad * 8];
                s8v q1 = *(const s8v*)&Wgm[(nt * 16 + c) * GP + 32 + quad * 8];
                accg[nt] = __builtin_amdgcn_mfma_f32_16x16x32_bf16(a0, q0, accg[nt], 0, 0, 0);
                accg[nt] = __builtin_amdgcn_mfma_f32_16x16x32_bf16(a1, q1, accg[nt], 0, 0, 0);
            }
        }
    }
#pragma unroll
    for (int nt = 0; nt < 4; ++nt) {
        int o = o0 + nt * 16 + c;
        float vv[4];
#pragma unroll
        for (int r = 0; r < 4; ++r) {
            float v = acc[nt][r] + (g.bias ? g.bias[o] : 0.f);
            if (geglu) {
                float gg = accg[nt][r] + g.bias[o + geglu_off];
                v = v * 0.5f * gg * (1.f + erff(gg * 0.70710678118654752f));
            }
            vv[r] = v;
        }
        if (g.ob_mode == 3) {
            int nb = n0 + w * 16 + quad * 4;
            const float4 x4 = *(const float4*)(res + (size_t)o * obT_stride + nb);
            float4 o4 = make_float4(vv[0] + x4.x, vv[1] + x4.y, vv[2] + x4.z, vv[3] + x4.w);
            *(float4*)(g.outf + (size_t)o * obT_stride + nb) = o4;
        } else {
#pragma unroll
            for (int r = 0; r < 4; ++r) {
                int n = n0 + w * 16 + quad * 4 + r;
                if (n >= Mrows) continue;
                float v = vv[r];
                if (res) v += res[(size_t)n * Oout + o];
                if (g.outf) g.outf[(size_t)n * Oout + o] = v;
                if (g.ob_mode == 1) g.outb[(size_t)n * Oout + o] = bf16u(v);
                else if (g.ob_mode == 2) g.outb[(size_t)o * obT_stride + n] = bf16u(v);
            }
        }
    }
}

// ---------------- Self-attention v4: K-split flash, partial numer/denom out ----------------
// grid (64 qtiles, 8 heads, 2 ksplit), 256 thr = 4 waves; 128-key tiles, 16 tiles per split.
#define KP 72
#define VP 136
__global__ __launch_bounds__(256) void attn_self4_k(const u16* __restrict__ qb, const u16* __restrict__ kb,
                                                    const u16* __restrict__ vt,
                                                    u16* __restrict__ Opart, float* __restrict__ lpart) {
    __shared__ __align__(16) u16 Ks[128 * KP];
    __shared__ __align__(16) u16 Vs[48 * VP];
    __shared__ __align__(16) u16 Ps[64 * VP];
    const int t = threadIdx.x;
    const int w = t >> 6, lane = t & 63, c = lane & 15, quad = lane >> 4;
    const int hd = blockIdx.y, ks = blockIdx.z;
    const int q0 = blockIdx.x * 64;
    const float SC2 = 0.15811388300841897f * 1.4426950408889634f;   // scale * log2(e)
    const f4v zero = {0.f, 0.f, 0.f, 0.f};
    const s8v z8 = {0, 0, 0, 0, 0, 0, 0, 0};

    for (int i = t; i < 128 * KP / 2; i += 256) ((unsigned*)Ks)[i] = 0u;
    for (int i = t; i < 48 * VP / 2; i += 256) ((unsigned*)Vs)[i] = 0u;

    const u16* qrow = qb + (size_t)(q0 + w * 16 + c) * DMODEL + hd * DHEAD;
    s8v qa0 = *(const s8v*)(qrow + quad * 8);
    s8v qa1 = z8;
    if (quad == 0) qa1 = *(const s8v*)(qrow + 32);

    float lacc[4] = {0.f, 0.f, 0.f, 0.f};
    f4v o0 = zero, o1 = zero, o2 = zero;
    __syncthreads();

    for (int kt = 0; kt < 16; ++kt) {
        const int k0 = ks * 2048 + kt * 128;
        __syncthreads();
        for (int i = t; i < 640; i += 256) {
            int r = i / 5, sg = i - r * 5;
            *(s8v*)&Ks[r * KP + sg * 8] = *(const s8v*)(kb + (size_t)(k0 + r) * DMODEL + hd * DHEAD + sg * 8);
        }
        for (int i = t; i < 640; i += 256) {
            int d = i >> 4, sg = i & 15;
            *(s8v*)&Vs[d * VP + sg * 8] = *(const s8v*)(vt + (size_t)(hd * DHEAD + d) * N_SEQ + k0 + sg * 8);
        }
        __syncthreads();

        f4v sarr[8];
#pragma unroll
        for (int h2 = 0; h2 < 2; ++h2)
#pragma unroll
            for (int nt = 0; nt < 4; ++nt) {
                const int kr = h2 * 64 + nt * 16 + c;
                s8v b0 = *(const s8v*)&Ks[kr * KP + quad * 8];
                s8v b1 = *(const s8v*)&Ks[kr * KP + 32 + quad * 8];
                f4v s = __builtin_amdgcn_mfma_f32_16x16x32_bf16(qa0, b0, zero, 0, 0, 0);
                s = __builtin_amdgcn_mfma_f32_16x16x32_bf16(qa1, b1, s, 0, 0, 0);
                sarr[h2 * 4 + nt] = s;
            }

#pragma unroll
        for (int reg = 0; reg < 8; ++reg) {
            int colb = (reg >> 2) * 64 + (reg & 3) * 16 + c;
#pragma unroll
            for (int r = 0; r < 4; ++r) {
                float pv = exp2f(sarr[reg][r] * SC2);
                lacc[r] += pv;
                Ps[(w * 16 + quad * 4 + r) * VP + colb] = (u16)((__float_as_uint(pv) + 0x8000u) >> 16);
            }
        }

#pragma unroll
        for (int h2 = 0; h2 < 2; ++h2) {
            s8v pa0 = *(const s8v*)&Ps[(w * 16 + c) * VP + h2 * 64 + quad * 8];
            s8v pa1 = *(const s8v*)&Ps[(w * 16 + c) * VP + h2 * 64 + 32 + quad * 8];
            {
                s8v v0 = *(const s8v*)&Vs[(0 * 16 + c) * VP + h2 * 64 + quad * 8];
                s8v v1 = *(const s8v*)&Vs[(0 * 16 + c) * VP + h2 * 64 + 32 + quad * 8];
                o0 = __builtin_amdgcn_mfma_f32_16x16x32_bf16(pa0, v0, o0, 0, 0, 0);
                o0 = __builtin_amdgcn_mfma_f32_16x16x32_bf16(pa1, v1, o0, 0, 0, 0);
            }
            {
                s8v v0 = *(const s8v*)&Vs[(1 * 16 + c) * VP + h2 * 64 + quad * 8];
                s8v v1 = *(const s8v*)&Vs[(1 * 16 + c) * VP + h2 * 64 + 32 + quad * 8];
                o1 = __builtin_amdgcn_mfma_f32_16x16x32_bf16(pa0, v0, o1, 0, 0, 0);
                o1 = __builtin_amdgcn_mfma_f32_16x16x32_bf16(pa1, v1, o1, 0, 0, 0);
            }
            {
                s8v v0 = *(const s8v*)&Vs[(2 * 16 + c) * VP + h2 * 64 + quad * 8];
                s8v v1 = *(const s8v*)&Vs[(2 * 16 + c) * VP + h2 * 64 + 32 + quad * 8];
                o2 = __builtin_amdgcn_mfma_f32_16x16x32_bf16(pa0, v0, o2, 0, 0, 0);
                o2 = __builtin_amdgcn_mfma_f32_16x16x32_bf16(pa1, v1, o2, 0, 0, 0);
            }
        }
    }

    const size_t pb = (size_t)(ks * 8 + hd) * N_SEQ;
#pragma unroll
    for (int r = 0; r < 4; ++r) {
        float l = lacc[r];
        l += __shfl_xor(l, 1); l += __shfl_xor(l, 2); l += __shfl_xor(l, 4); l += __shfl_xor(l, 8);
        int q = q0 + w * 16 + quad * 4 + r;
        u16* op = Opart + (pb + q) * DHEAD;
        op[c]      = bf16u(o0[r]);
        op[16 + c] = bf16u(o1[r]);
        if (c < 8) op[32 + c] = bf16u(o2[r]);
        if (c == 0) lpart[pb + q] = l;
    }
}

// ---------------- attention combine: ao[n][c] = (O0+O1)/(l0+l1) ----------------
__global__ __launch_bounds__(256) void attn_comb_k(const u16* __restrict__ Opart, const float* __restrict__ lpart,
                                                   u16* __restrict__ ao) {
    int idx = blockIdx.x * 256 + threadIdx.x;   // < 1310720
    int n = idx / DMODEL, c = idx - n * DMODEL;
    int hd = c / DHEAD, d = c - hd * DHEAD;
    size_t b0 = ((size_t)hd * N_SEQ + n) * DHEAD + d;
    size_t b1 = ((size_t)(8 + hd) * N_SEQ + n) * DHEAD + d;
    float num = b2f(Opart[b0]) + b2f(Opart[b1]);
    float den = lpart[(size_t)hd * N_SEQ + n] + lpart[(size_t)(8 + hd) * N_SEQ + n];
    ao[idx] = bf16u(num / den);
}

// ---------------- Cross-attention (M=77): one wave per (row, head) ----------------
__global__ __launch_bounds__(256) void attn_cross2_k(const u16* __restrict__ q, const float* __restrict__ kc,
                                                     const float* __restrict__ vc, u16* __restrict__ out) {
    __shared__ float Pl[4][128];
    const int t = threadIdx.x, w = t >> 6, l = t & 63;
    const int gw = blockIdx.x * 4 + w;
    const int row = gw >> 3, hd = gw & 7;
    const float scale = 0.15811388300841897f;
    float qv[40];
    {
        const u16* qp = q + (size_t)row * DMODEL + hd * DHEAD;
#pragma unroll
        for (int i = 0; i < 5; ++i) {
            s8v v8 = *(const s8v*)(qp + i * 8);
#pragma unroll
            for (int j = 0; j < 8; ++j) qv[i * 8 + j] = b2f((u16)v8[j]) * scale;
        }
    }
    float s1 = -1e30f, s2 = -1e30f;
    if (l < CTXN) {
        const float* kp = kc + (size_t)l * DMODEL + hd * DHEAD;
        float s = 0.f;
#pragma unroll
        for (int i = 0; i < 40; ++i) s += qv[i] * kp[i];
        s1 = s;
    }
    if (l + 64 < CTXN) {
        const float* kp = kc + (size_t)(l + 64) * DMODEL + hd * DHEAD;
        float s = 0.f;
#pragma unroll
        for (int i = 0; i < 40; ++i) s += qv[i] * kp[i];
        s2 = s;
    }
    float mx = fmaxf(s1, s2);
    for (int o = 32; o > 0; o >>= 1) mx = fmaxf(mx, __shfl_xor(mx, o));
    float p1 = (l < CTXN) ? __expf(s1 - mx) : 0.f;
    float p2 = (l + 64 < CTXN) ? __expf(s2 - mx) : 0.f;
    float ps = p1 + p2;
    for (int o = 32; o > 0; o >>= 1) ps += __shfl_xor(ps, o);
    Pl[w][l] = p1;
    Pl[w][l + 64] = p2;
    if (l < DHEAD) {
        float acc = 0.f;
        for (int j = 0; j < CTXN; ++j) acc += Pl[w][j] * vc[(size_t)j * DMODEL + hd * DHEAD + l];
        out[(size_t)row * DMODEL + hd * DHEAD + l] = bf16u(acc / ps);
    }
}

extern "C" void kernel_launch(void* const* d_in, const int* in_sizes, int n_in,
                              void* d_out, int out_size, void* d_ws, size_t ws_size,
                              hipStream_t stream) {
    const float* x      = (const float*)d_in[0];
    const float* ctx    = (const float*)d_in[1];
    const float* gn_w   = (const float*)d_in[2];
    const float* gn_b   = (const float*)d_in[3];
    const float* pin_w  = (const float*)d_in[4];
    const float* pin_b  = (const float*)d_in[5];
    const float* ln1_w  = (const float*)d_in[6];
    const float* ln1_b  = (const float*)d_in[7];
    const float* q1     = (const float*)d_in[8];
    const float* k1     = (const float*)d_in[9];
    const float* v1     = (const float*)d_in[10];
    const float* o1_w   = (const float*)d_in[11];
    const float* o1_b   = (const float*)d_in[12];
    const float* ln2_w  = (const float*)d_in[13];
    const float* ln2_b  = (const float*)d_in[14];
    const float* q2     = (const float*)d_in[15];
    const float* k2     = (const float*)d_in[16];
    const float* v2     = (const float*)d_in[17];
    const float* o2_w   = (const float*)d_in[18];
    const float* o2_b   = (const float*)d_in[19];
    const float* ln3_w  = (const float*)d_in[20];
    const float* ln3_b  = (const float*)d_in[21];
    const float* ff1_w  = (const float*)d_in[22];
    const float* ff1_b  = (const float*)d_in[23];
    const float* ff2_w  = (const float*)d_in[24];
    const float* ff2_b  = (const float*)d_in[25];
    const float* pout_w = (const float*)d_in[26];
    const float* pout_b = (const float*)d_in[27];
    float* out = (float*)d_out;

    char* base = (char*)d_ws;
    float* h     = (float*)(base);                        //  0.00 .. 5.24 MB  f32 [4096][320]
    u16*   qb16  = (u16*)(base + 5242880);                //  5.24 .. 7.86
    u16*   kb16  = (u16*)(base + 7864320);                //  7.86 .. 10.49
    u16*   vt16  = (u16*)(base + 10485760);               // 10.49 .. 13.11  [320][4096]
    u16*   ao16  = (u16*)(base + 13107200);               // 13.11 .. 15.73
    u16*   ffg16 = (u16*)(base + 5242880);                // FF phase alias: 5.24..15.73 ( [4096][1280] )
    u16*   wbase = (u16*)(base + 15728640);               // 15.73 .. 20.81  bf16 weights
    u16* pinT  = wbase;
    u16* q1T   = pinT  + 102400;
    u16* k1T   = q1T   + 102400;
    u16* v1T   = k1T   + 102400;
    u16* o1T   = v1T   + 102400;
    u16* q2T   = o1T   + 102400;
    u16* o2T   = q2T   + 102400;
    u16* k2T   = o2T   + 102400;
    u16* v2T   = k2T   + 245760;
    u16* ff1T  = v2T   + 245760;
    u16* ff2T  = ff1T  + 819200;
    u16* poutT = ff2T  + 409600;                          // ends 15728640+5079040 B = 20,807,680
    float* gnsc = (float*)(base + 20807680);              // 320
    float* gnsh = gnsc + 320;
    float* lnmu = gnsh + 320;                             // 4096
    float* lnrs = lnmu + 4096;                            // 4096
    float* k2f  = lnrs + 4096;                            // 77*320 (pad 25600)
    float* v2f  = k2f + 25600;
    u16*   Opart = (u16*)(v2f + 25600);                   // 2*8*4096*40 bf16 = 5.24 MB
    float* lpart = (float*)(Opart + 2 * 8 * 4096 * 40);   // 2*8*4096 f32 -> total ~26.5 MB

    // 0. weights -> bf16 [O][K]
    WCs wd;
    wd.a[0]  = {pin_w,  pinT,  320,  320,  0};
    wd.a[1]  = {q1,     q1T,   320,  320,  1};
    wd.a[2]  = {k1,     k1T,   320,  320,  1};
    wd.a[3]  = {v1,     v1T,   320,  320,  1};
    wd.a[4]  = {o1_w,   o1T,   320,  320,  1};
    wd.a[5]  = {q2,     q2T,   320,  320,  1};
    wd.a[6]  = {o2_w,   o2T,   320,  320,  1};
    wd.a[7]  = {k2,     k2T,   768,  320,  1};
    wd.a[8]  = {v2,     v2T,   768,  320,  1};
    wd.a[9]  = {ff1_w,  ff1T,  320,  2560, 1};
    wd.a[10] = {ff2_w,  ff2T,  1280, 320,  1};
    wd.a[11] = {pout_w, poutT, 320,  320,  0};
    wcast_k<<<dim3(3200, 12), 256, 0, stream>>>(wd);

    GArg gz = {nullptr, nullptr, nullptr, nullptr, 0};

    // 1. GN stats -> per-channel coef; proj_in with GN fused in staging
    gn_stats_k<<<32, 256, 0, stream>>>(x, gn_w, gn_b, gnsc, gnsh);
    {
        GArg g0 = {pinT, pin_b, h, nullptr, 0};
        gemm_v3<<<dim3(5, 64, 1), 256, 0, stream>>>(x, 2, 4096, nullptr, nullptr, gnsc, gnsh,
                                                    g0, gz, gz, nullptr, 4096, 320, 320, 0, 0);
    }
    // 2. self-attention block (LN1 fused into qkv staging)
    ln_stats_k<<<1024, 256, 0, stream>>>(h, lnmu, lnrs);
    {
        GArg g0 = {q1T, nullptr, nullptr, qb16, 1};
        GArg g1 = {k1T, nullptr, nullptr, kb16, 1};
        GArg g2 = {v1T, nullptr, nullptr, vt16, 2};
        gemm_v3<<<dim3(5, 64, 3), 256, 0, stream>>>(h, 3, 320, lnmu, lnrs, ln1_w, ln1_b,
                                                    g0, g1, g2, nullptr, 4096, 320, 320, 0, 4096);
    }
    attn_self4_k<<<dim3(64, 8, 2), 256, 0, stream>>>(qb16, kb16, vt16, Opart, lpart);
    attn_comb_k<<<5120, 256, 0, stream>>>(Opart, lpart, ao16);
    {
        GArg g0 = {o1T, o1_b, h, nullptr, 0};
        gemm_v3<<<dim3(5, 64, 1), 256, 0, stream>>>(ao16, 0, 320, nullptr, nullptr, nullptr, nullptr,
                                                    g0, gz, gz, h, 4096, 320, 320, 0, 0);
    }
    // 3. cross-attention block (LN2 fused into q2 staging)
    ln_stats_k<<<1024, 256, 0, stream>>>(h, lnmu, lnrs);
    {
        GArg g0 = {q2T, nullptr, nullptr, qb16, 1};
        gemm_v3<<<dim3(5, 64, 1), 256, 0, stream>>>(h, 3, 320, lnmu, lnrs, ln2_w, ln2_b,
                                                    g0, gz, gz, nullptr, 4096, 320, 320, 0, 0);
    }
    {
        GArg g0 = {k2T, nullptr, k2f, nullptr, 0};
        GArg g1 = {v2T, nullptr, v2f, nullptr, 0};
        gemm_v3<<<dim3(5, 2, 2), 256, 0, stream>>>(ctx, 1, 768, nullptr, nullptr, nullptr, nullptr,
                                                   g0, g1, gz, nullptr, 77, 768, 320, 0, 0);
    }
    attn_cross2_k<<<8192, 256, 0, stream>>>(qb16, k2f, v2f, ao16);
    {
        GArg g0 = {o2T, o2_b, h, nullptr, 0};
        gemm_v3<<<dim3(5, 64, 1), 256, 0, stream>>>(ao16, 0, 320, nullptr, nullptr, nullptr, nullptr,
                                                    g0, gz, gz, h, 4096, 320, 320, 0, 0);
    }
    // 4. GEGLU FF (LN3 fused into ff1 staging; full 4096 rows)
    ln_stats_k<<<1024, 256, 0, stream>>>(h, lnmu, lnrs);
    {
        GArg g0 = {ff1T, ff1_b, nullptr, ffg16, 1};
        gemm_v3<<<dim3(20, 64, 1), 256, 0, stream>>>(h, 3, 320, lnmu, lnrs, ln3_w, ln3_b,
                                                     g0, gz, gz, nullptr, 4096, 320, 1280, 1280, 0);
    }
    {
        GArg g0 = {ff2T, ff2_b, h, nullptr, 0};
        gemm_v3<<<dim3(5, 64, 1), 256, 0, stream>>>(ffg16, 0, 1280, nullptr, nullptr, nullptr, nullptr,
                                                    g0, gz, gz, h, 4096, 1280, 320, 0, 0);
    }
    // 5. proj_out + input residual, transposed epilogue straight to out
    {
        GArg g0 = {poutT, pout_b, out, nullptr, 3};
        gemm_v3<<<dim3(5, 64, 1), 256, 0, stream>>>(h, 1, 320, nullptr, nullptr, nullptr, nullptr,
                                                    g0, gz, gz, x, 4096, 320, 320, 0, 4096);
    }
}